// Round 12
// baseline (276.636 us; speedup 1.0000x reference)
//
#include <hip/hip_runtime.h>
#include <hip/hip_bf16.h>
#include <stdint.h>

// ---------------- problem constants ----------------
#define LTOK  1025      // 1024 body + 1 cls
#define NROWS 2050      // B * LTOK
#define DM    512
#define DIN   1024
#define DST   128
#define NHEAD 16
#define HDIM  64
#define CDIM  1280      // DIN + 2*DST
#define EPROJ 2320      // 2*DIN + 2*DST + NHEAD
#define QC    64        // SSD chunk length
#define NCH   17        // ceil(1025/64)

// ---------------- workspace layout (float offsets), ~65.0 MB ----------------
#define O_RIDX   0          // int32 x 514 (reserve 1024)
#define O_CB     1024
#define O_CLS    1536
#define O_C1B    2048
#define O_DTB    3328
#define O_ALOG   3344
#define O_DV     3360
#define O_RMSW   3376
#define O_LNG    4400
#define O_LNB    4912
#define O_CW     5440
#define O_IPW    103744
#define O_OPW    1291584
#define O_C1W    1815872
#define O_CX     1820992
#define O_ZX     1952064
#define O_XBC    6708064
#define O_DT     9332064
#define O_LGA    9364864    // log(dA) = dt * (-exp(A_log))
#define O_Y      9397664    // 2,099,200 floats; overlays H and X3 (dead after in_proj)
#define O_H      9397664    // 1,049,600
#define O_X3     10447264   // 393,216
#define O_OUTG   11496864   // 263,168
#define O_SL     11760032   // chunk states: 32*17*8192 (S_loc, then in-place S_start)
#define O_CLA    16216480   // within-chunk cumsum logdA: 32*17*64
#define O_KM     16251296   // int32 keep-mask, NROWS entries -> ends 16,253,346

// ---------------- output layout (FLOAT32 elements) ----------------
#define OO_MASK 263168
#define OO_IDR  265216
#define OO_IDK  267264

typedef __attribute__((ext_vector_type(8))) short short8;
typedef __attribute__((ext_vector_type(4))) short shortx4;
typedef __attribute__((ext_vector_type(4))) float floatx4;

__device__ __forceinline__ short f2bs(float f) {
  union { float f; uint32_t u; } v; v.f = f;
  uint32_t r = (v.u + 0x7FFFu + ((v.u >> 16) & 1u)) >> 16;
  return (short)r;
}

struct InPtrs { const void* p[14]; };

// ---------------- input dtype detect + convert to f32 ----------------
__device__ int detect_is_f32(const uint32_t* w, int nelem) {
  int nw = nelem / 2; if (nw > 16) nw = 16;
  int insane = 0, lozero = 0, anynz = 0;
  for (int i = 0; i < nw; ++i) {
    uint32_t word = w[i];
    if (word != 0u) anynz = 1;
    uint32_t lo = word & 0xffffu;
    if (lo == 0u) { lozero++; continue; }
    float v = __uint_as_float(lo << 16);
    float a = fabsf(v);
    if (!(a >= 1e-8f && a <= 1e4f)) insane++;
  }
  if (insane >= 2) return 1;
  if (lozero == nw && anynz) return 1;
  return 0;
}

__global__ __launch_bounds__(256) void k_convert(InPtrs ptrs, float* ws) {
  static const int sizes[14] = {131072, 98304, 512, 512, 1187840, 5120, 1280,
                                16, 16, 16, 1024, 524288, 512, 512};
  static const int offs[14]  = {O_CX, O_CW, O_CB, O_CLS, O_IPW, O_C1W, O_C1B,
                                O_DTB, O_ALOG, O_DV, O_RMSW, O_OPW, O_LNG, O_LNB};
  int t = blockIdx.y;
  int n = sizes[t];
  const uint32_t* w = (const uint32_t*)ptrs.p[t];
  __shared__ int sf;
  if (threadIdx.x == 0) sf = detect_is_f32(w, n);
  __syncthreads();
  int base = (blockIdx.x * 256 + threadIdx.x) * 4;
  if (base >= n) return;
  float* dst = ws + offs[t];
  if (sf) {
    *(float4*)(dst + base) = *(const float4*)((const float*)w + base);
  } else {
    const uint32_t* s = w + (base >> 1);
    uint32_t w0 = s[0], w1 = s[1];
    float4 o;
    o.x = __uint_as_float((w0 & 0xffffu) << 16);
    o.y = __uint_as_float(w0 & 0xffff0000u);
    o.z = __uint_as_float((w1 & 0xffffu) << 16);
    o.w = __uint_as_float(w1 & 0xffff0000u);
    *(float4*)(dst + base) = o;
  }
}

// ---------------- zero a float region ----------------
__global__ __launch_bounds__(256) void k_zero(float* __restrict__ p, int n) {
  int e = (blockIdx.x * 256 + threadIdx.x) * 4;
  if (e < n) *(float4*)(p + e) = make_float4(0.f, 0.f, 0.f, 0.f);
}

// ---------------- threefry2x32 (JAX-compatible) ----------------
__device__ __forceinline__ uint32_t rotl32(uint32_t v, int d) {
  return (v << d) | (v >> (32 - d));
}
__device__ void threefry2x32(uint32_t k0, uint32_t k1, uint32_t c0, uint32_t c1,
                             uint32_t& o0, uint32_t& o1) {
  uint32_t ks0 = k0, ks1 = k1, ks2 = 0x1BD11BDAu ^ k0 ^ k1;
  uint32_t x0 = c0 + ks0, x1 = c1 + ks1;
#define TF_R4(a,b,c,d) \
  x0 += x1; x1 = rotl32(x1,a); x1 ^= x0; \
  x0 += x1; x1 = rotl32(x1,b); x1 ^= x0; \
  x0 += x1; x1 = rotl32(x1,c); x1 ^= x0; \
  x0 += x1; x1 = rotl32(x1,d); x1 ^= x0;
  TF_R4(13,15,26,6)  x0 += ks1; x1 += ks2 + 1u;
  TF_R4(17,29,16,24) x0 += ks2; x1 += ks0 + 2u;
  TF_R4(13,15,26,6)  x0 += ks0; x1 += ks1 + 3u;
  TF_R4(17,29,16,24) x0 += ks1; x1 += ks2 + 4u;
  TF_R4(13,15,26,6)  x0 += ks2; x1 += ks0 + 5u;
#undef TF_R4
  o0 = x0; o1 = x1;
}

// RNG + stable argsort ranks + keep-mask. grid (16, 2); 64 targets/block,
// 4 threads/target scanning 256-element quarters, shfl-combined.
__global__ __launch_bounds__(256) void k_rng(float* out, int* rowidx, int* km) {
  int b = blockIdx.y;
  int seg = blockIdx.x;
  int tid = threadIdx.x;
  __shared__ float vals[1024];
  uint32_t fk0, fk1;
  threefry2x32(0u, 0u, 0u, 1u, fk0, fk1);          // fold_in(key(0), 1)
#pragma unroll
  for (int k = 0; k < 4; ++k) {
    int i = tid + k * 256;
    uint32_t o0, o1;
    threefry2x32(fk0, fk1, 0u, (uint32_t)(b * 1024 + i), o0, o1);
    uint32_t bits = o0 ^ o1;
    vals[i] = __uint_as_float((bits >> 9) | 0x3f800000u) - 1.0f;
  }
  __syncthreads();
  int tg = seg * 64 + (tid >> 2);      // target index
  int qq = tid & 3;                    // quarter
  float v = vals[tg];
  int r = 0;
  int j0 = qq * 256;
  for (int it = 0; it < 256; ++it) {
    int j = j0 + ((it + qq * 8) & 255);
    float vj = vals[j];
    r += (vj < v || (vj == v && j < tg)) ? 1 : 0;
  }
  r += __shfl_xor(r, 1, 64);
  r += __shfl_xor(r, 2, 64);
  if (qq == 0) {
    out[OO_IDR + b * 1024 + tg] = (float)r;
    out[OO_MASK + b * 1024 + tg] = (r < 256) ? 0.0f : 1.0f;
    km[b * LTOK + tg] = (r < 256) ? 1 : 0;
    if (r < 256) {
      out[OO_IDK + b * 256 + r] = (float)tg;
      rowidx[b * 257 + r] = b * LTOK + tg;
    }
    if (tg == 0) {
      rowidx[b * 257 + 256] = b * LTOK + 1024;
      km[b * LTOK + 1024] = 1;
    }
  }
}

// ---------------- im2col for conv-embed ----------------
__global__ void k_im2col(const float* __restrict__ x, float* __restrict__ X3) {
  int r = blockIdx.x;
  int b = r >> 10, t = r & 1023;
  int j = threadIdx.x;
  if (j < 192) {
    int i = j / 3, k = j % 3;
    int tt = t + k - 1;
    float v = (tt >= 0 && tt < 1024) ? x[((long)(b * 1024 + tt)) * 64 + i] : 0.f;
    X3[(long)r * 192 + j] = v;
  }
}

__global__ void k_clsrow(const float* __restrict__ cls, float* __restrict__ h) {
  h[((long)(blockIdx.x * LTOK + 1024)) * DM + threadIdx.x] = cls[threadIdx.x];
}

// ---------------- MFMA bf16 GEMM: C = A @ Bw^T (+bias), f32 in/out ----------------
// 128x128 tile, double-buffered LDS, optional split-K (atomicAdd epilogue, C pre-zeroed).
// cmode: 0 -> crow=r; 1 -> cls-gap remap; 2 -> crow=rowmap[r] (gathered A and C).
__global__ __launch_bounds__(256) void k_bgemm(
    const float* __restrict__ A, const float* __restrict__ Bw,
    float* __restrict__ C, const float* __restrict__ bias,
    const int* __restrict__ rowmap, int M, int N, int K, int ldc, int cmode) {
  __shared__ __align__(16) short sA[2][128 * 40];
  __shared__ __align__(16) short sB[2][128 * 40];
  int tid = threadIdx.x;
  int lane = tid & 63, w = tid >> 6;
  int lm = lane & 15, q = lane >> 4;
  int wm = (w >> 1) * 64, wn = (w & 1) * 64;
  int bm = blockIdx.y * 128, bn = blockIdx.x * 128;
  int gz = gridDim.z;
  int Ks = K / gz;
  int kbase = blockIdx.z * Ks;
  int nk = Ks >> 5;

  int srow[4], scol[4];
  long aoff[4]; bool aok[4]; long boff[4]; bool bok[4];
#pragma unroll
  for (int it = 0; it < 4; ++it) {
    int e4 = (tid + it * 256) * 4;
    srow[it] = e4 >> 5; scol[it] = e4 & 31;
    int gm = bm + srow[it];
    aok[it] = gm < M;
    aoff[it] = aok[it] ? (long)(rowmap ? rowmap[gm] : gm) * K : 0;
    int gn = bn + srow[it];
    bok[it] = gn < N;
    boff[it] = bok[it] ? (long)gn * K : 0;
  }

  auto gload = [&](int kt, float4* va, float4* vb) {
    int kc = kbase + kt * 32;
#pragma unroll
    for (int it = 0; it < 4; ++it) {
      va[it] = aok[it] ? *(const float4*)(A + aoff[it] + kc + scol[it])
                       : make_float4(0.f, 0.f, 0.f, 0.f);
      vb[it] = bok[it] ? *(const float4*)(Bw + boff[it] + kc + scol[it])
                       : make_float4(0.f, 0.f, 0.f, 0.f);
    }
  };
  auto sstore = [&](int buf, const float4* va, const float4* vb) {
#pragma unroll
    for (int it = 0; it < 4; ++it) {
      *(shortx4*)&sA[buf][srow[it] * 40 + scol[it]] =
          shortx4{f2bs(va[it].x), f2bs(va[it].y), f2bs(va[it].z), f2bs(va[it].w)};
      *(shortx4*)&sB[buf][srow[it] * 40 + scol[it]] =
          shortx4{f2bs(vb[it].x), f2bs(vb[it].y), f2bs(vb[it].z), f2bs(vb[it].w)};
    }
  };

  floatx4 acc[4][4] = {};
  float4 va[4], vb[4], na[4], nb[4];

  gload(0, va, vb);
  sstore(0, va, vb);
  for (int kt = 0; kt < nk; ++kt) {
    int cur = kt & 1;
    if (kt + 1 < nk) gload(kt + 1, na, nb);
    __syncthreads();
    short8 afrag[4], bfrag[4];
#pragma unroll
    for (int i = 0; i < 4; ++i)
      afrag[i] = *(const short8*)&sA[cur][(wm + i * 16 + lm) * 40 + q * 8];
#pragma unroll
    for (int j = 0; j < 4; ++j)
      bfrag[j] = *(const short8*)&sB[cur][(wn + j * 16 + lm) * 40 + q * 8];
#pragma unroll
    for (int i = 0; i < 4; ++i)
#pragma unroll
      for (int j = 0; j < 4; ++j)
        acc[i][j] = __builtin_amdgcn_mfma_f32_16x16x32_bf16(afrag[i], bfrag[j], acc[i][j], 0, 0, 0);
    if (kt + 1 < nk) sstore(1 - cur, na, nb);
  }

#pragma unroll
  for (int i = 0; i < 4; ++i) {
    int rowl = wm + i * 16 + q * 4;
#pragma unroll
    for (int reg = 0; reg < 4; ++reg) {
      int r = bm + rowl + reg;
      if (r >= M) continue;
      long crow;
      if (cmode == 1) crow = (long)((r >> 10) * LTOK + (r & 1023));
      else if (cmode == 2) crow = (long)rowmap[r];
      else crow = (long)r;
#pragma unroll
      for (int j = 0; j < 4; ++j) {
        int ccol = bn + wn + j * 16 + lm;
        if (ccol < N) {
          float v = acc[i][j][reg];
          if (gz > 1) {
            atomicAdd(&C[crow * ldc + ccol], v);
          } else {
            if (bias) v += bias[ccol];
            C[crow * ldc + ccol] = v;
          }
        }
      }
    }
  }
}

// ---------------- depthwise causal conv(4) + silu (round-10 parallel form) ----------------
__global__ __launch_bounds__(256) void k_conv1d(const float* __restrict__ zx,
                                                const float* __restrict__ w,
                                                const float* __restrict__ bias,
                                                float* __restrict__ xbc) {
  long r = blockIdx.x;
  int b = (int)(r / LTOK), t = (int)(r % LTOK);
  for (int c = threadIdx.x; c < CDIM; c += 256) {
    float acc = bias[c];
    const float* wp = w + c * 4;
#pragma unroll
    for (int k = 0; k < 4; ++k) {
      int tt = t - 3 + k;
      if (tt >= 0)
        acc = fmaf(wp[k], zx[((long)(b * LTOK + tt)) * EPROJ + DIN + c], acc);
    }
    xbc[r * CDIM + c] = acc / (1.f + expf(-acc));
  }
}

// ---------------- dt = softplus(logit + bias), lga = dt * -exp(A_log) ----------------
__global__ void k_dtda(const float* __restrict__ zx, const float* __restrict__ dtb,
                       const float* __restrict__ alog, float* __restrict__ dt,
                       float* __restrict__ lga) {
  int idx = blockIdx.x * 256 + threadIdx.x;
  if (idx >= NROWS * NHEAD) return;
  int r = idx >> 4, h = idx & 15;
  float xv = zx[(long)r * EPROJ + (EPROJ - NHEAD) + h] + dtb[h];
  float dtv = (xv > 20.f) ? xv : log1pf(expf(xv));
  dt[idx] = dtv;
  lga[idx] = dtv * (-expf(alog[h]));
}

// ---------------- SSD phase 1 (MFMA bf16): per (b,h,chunk) intra-chunk work ----------------
__global__ __launch_bounds__(256) void k_ssd1(const float* __restrict__ xbc,
                                              const float* __restrict__ dt,
                                              const float* __restrict__ lga,
                                              float* __restrict__ Y,
                                              float* __restrict__ SL,
                                              float* __restrict__ CLA,
                                              const int* __restrict__ km) {
  int blk = blockIdx.x;
  int c = blk % NCH;
  int hh = blk / NCH;            // h + 16*b
  int h = hh & 15, b = hh >> 4;
  int tid = threadIdx.x;
  int lane = tid & 63, w = tid >> 6;
  int lm = lane & 15, q = lane >> 4;

  __shared__ __align__(16) short sB[64 * 136];
  __shared__ __align__(16) short sC[64 * 136];
  __shared__ __align__(16) short sBT[128 * 72];
  __shared__ __align__(16) short sXT[64 * 72];
  __shared__ __align__(16) short sM[64 * 72];
  __shared__ float dtw[64], clA[64], wwv[64];

  int t0 = c * QC;
  const float* base = xbc + (long)b * LTOK * CDIM;

  if (tid < 64) {
    int t = t0 + tid;
    dtw[tid] = (t < LTOK) ? dt[((long)(b * LTOK + t)) * NHEAD + h] : 0.f;
    clA[tid] = (t < LTOK) ? lga[((long)(b * LTOK + t)) * NHEAD + h] : 0.f;
  }
  __syncthreads();
  if (tid == 0) {
    float s = 0.f;
    for (int i = 0; i < 64; ++i) { s += clA[i]; clA[i] = s; }
  }
  __syncthreads();
  float clEnd = clA[63];
  if (tid < 64) {
    wwv[tid] = __expf(clEnd - clA[tid]) * dtw[tid];
    CLA[(long)blk * 64 + tid] = clA[tid];
  }
  __syncthreads();

#pragma unroll
  for (int k = 0; k < 8; ++k) {
    int e4 = (tid + k * 256) * 4;
    int row = e4 >> 7, col = e4 & 127;
    int t = t0 + row;
    float4 bv = make_float4(0.f,0.f,0.f,0.f), cv = make_float4(0.f,0.f,0.f,0.f);
    if (t < LTOK) {
      const float* rp = base + (long)t * CDIM;
      bv = *(const float4*)(rp + DIN + col);
      cv = *(const float4*)(rp + DIN + DST + col);
    }
    float wv = wwv[row];
    sB[row*136+col]=f2bs(bv.x); sB[row*136+col+1]=f2bs(bv.y);
    sB[row*136+col+2]=f2bs(bv.z); sB[row*136+col+3]=f2bs(bv.w);
    sC[row*136+col]=f2bs(cv.x); sC[row*136+col+1]=f2bs(cv.y);
    sC[row*136+col+2]=f2bs(cv.z); sC[row*136+col+3]=f2bs(cv.w);
    sBT[(col  )*72+row]=f2bs(bv.x*wv); sBT[(col+1)*72+row]=f2bs(bv.y*wv);
    sBT[(col+2)*72+row]=f2bs(bv.z*wv); sBT[(col+3)*72+row]=f2bs(bv.w*wv);
  }
#pragma unroll
  for (int k = 0; k < 4; ++k) {
    int e4 = (tid + k * 256) * 4;
    int row = e4 >> 6, col = e4 & 63;
    int t = t0 + row;
    float4 xv = make_float4(0.f,0.f,0.f,0.f);
    if (t < LTOK) xv = *(const float4*)(base + (long)t * CDIM + h * 64 + col);
    sXT[(col  )*72+row]=f2bs(xv.x); sXT[(col+1)*72+row]=f2bs(xv.y);
    sXT[(col+2)*72+row]=f2bs(xv.z); sXT[(col+3)*72+row]=f2bs(xv.w);
  }
  __syncthreads();

  floatx4 g[4] = {};
#pragma unroll
  for (int kb = 0; kb < 4; ++kb) {
    short8 a = *(const short8*)&sC[(w*16 + lm)*136 + kb*32 + q*8];
#pragma unroll
    for (int ct = 0; ct < 4; ++ct) {
      short8 bb = *(const short8*)&sB[(ct*16 + lm)*136 + kb*32 + q*8];
      g[ct] = __builtin_amdgcn_mfma_f32_16x16x32_bf16(a, bb, g[ct], 0, 0, 0);
    }
  }
#pragma unroll
  for (int ct = 0; ct < 4; ++ct) {
    int tp = ct*16 + lm;
#pragma unroll
    for (int reg = 0; reg < 4; ++reg) {
      int tl = w*16 + q*4 + reg;
      float m = 0.f;
      if (tp <= tl) m = g[ct][reg] * __expf(clA[tl] - clA[tp]) * dtw[tp];
      sM[tl*72 + tp] = f2bs(m);
    }
  }
  __syncthreads();

  floatx4 y[4] = {};
#pragma unroll
  for (int kb = 0; kb < 2; ++kb) {
    short8 a = *(const short8*)&sM[(w*16 + lm)*72 + kb*32 + q*8];
#pragma unroll
    for (int ct = 0; ct < 4; ++ct) {
      short8 bb = *(const short8*)&sXT[(ct*16 + lm)*72 + kb*32 + q*8];
      y[ct] = __builtin_amdgcn_mfma_f32_16x16x32_bf16(a, bb, y[ct], 0, 0, 0);
    }
  }
#pragma unroll
  for (int reg = 0; reg < 4; ++reg) {
    int t = t0 + w*16 + q*4 + reg;
    bool keep = (t < LTOK) && km[(long)b * LTOK + t];
    if (keep) {
#pragma unroll
      for (int ct = 0; ct < 4; ++ct)
        Y[((long)(b * LTOK + t)) * DIN + h * 64 + ct*16 + lm] = y[ct][reg];
    }
  }

  floatx4 s[2][4] = {};
#pragma unroll
  for (int kb = 0; kb < 2; ++kb) {
    short8 bfr[4];
#pragma unroll
    for (int ct = 0; ct < 4; ++ct)
      bfr[ct] = *(const short8*)&sXT[(ct*16 + lm)*72 + kb*32 + q*8];
#pragma unroll
    for (int nt = 0; nt < 2; ++nt) {
      short8 a = *(const short8*)&sBT[((w*2+nt)*16 + lm)*72 + kb*32 + q*8];
#pragma unroll
      for (int ct = 0; ct < 4; ++ct)
        s[nt][ct] = __builtin_amdgcn_mfma_f32_16x16x32_bf16(a, bfr[ct], s[nt][ct], 0, 0, 0);
    }
  }
  float* slp = SL + (long)blk * 8192;
#pragma unroll
  for (int nt = 0; nt < 2; ++nt)
#pragma unroll
    for (int ct = 0; ct < 4; ++ct)
#pragma unroll
      for (int reg = 0; reg < 4; ++reg) {
        int n = (w*2+nt)*16 + q*4 + reg;
        int p = ct*16 + lm;
        slp[n*64 + p] = s[nt][ct][reg];
      }
}

// ---------------- SSD phase 2a: in-place sequential combine over chunks ----------------
__global__ __launch_bounds__(256) void k_comb(float* __restrict__ SL,
                                              const float* __restrict__ CLA) {
  int bx = blockIdx.x;
  int piece = bx & 7;
  int hh = bx >> 3;
  int off = piece * 1024 + threadIdx.x * 4;
  float4 s = make_float4(0.f, 0.f, 0.f, 0.f);
  for (int c = 0; c < NCH; ++c) {
    long cb = (long)(hh * NCH + c);
    float* p = SL + cb * 8192 + off;
    float P = __expf(CLA[cb * 64 + 63]);
    float4 tmp = *(float4*)p;
    *(float4*)p = s;
    s.x = fmaf(P, s.x, tmp.x);
    s.y = fmaf(P, s.y, tmp.y);
    s.z = fmaf(P, s.z, tmp.z);
    s.w = fmaf(P, s.w, tmp.w);
  }
}

// ---------------- SSD phase 2b: Y += evec[t] * C_t . S_start (kept rows only) ----------------
__global__ __launch_bounds__(256) void k_ssd3(const float* __restrict__ xbc,
                                              const float* __restrict__ SL,
                                              const float* __restrict__ CLA,
                                              float* __restrict__ Y,
                                              const int* __restrict__ km) {
  int blk = blockIdx.x;
  int c = blk % NCH;
  int hh = blk / NCH;
  int h = hh & 15, b = hh >> 4;
  int tid = threadIdx.x;
  int tx = tid & 15, ty = tid >> 4;

  __shared__ float Cs[64 * 65];
  __shared__ float Ss[64 * 64];
  __shared__ float evec[64];

  int t0 = c * QC;
  const float* base = xbc + (long)b * LTOK * CDIM;
  const float* slp = SL + (long)blk * 8192;
  if (tid < 64) evec[tid] = __expf(CLA[(long)blk * 64 + tid]);

  float y[4][4] = {};
#pragma unroll
  for (int half = 0; half < 2; ++half) {
    int n0 = half * 64;
    __syncthreads();
#pragma unroll
    for (int k = 0; k < 16; ++k) {
      int e = tid + k * 256;
      int row = e >> 6, col = e & 63;
      int t = t0 + row;
      Cs[row * 65 + col] = (t < LTOK) ? base[(long)t * CDIM + DIN + DST + n0 + col] : 0.f;
    }
#pragma unroll
    for (int k = 0; k < 4; ++k) {
      int e = (tid + k * 256) * 4;
      *(float4*)(Ss + e) = *(const float4*)(slp + n0 * 64 + e);
    }
    __syncthreads();
    for (int n = 0; n < 64; ++n) {
      float cv[4], sv[4];
#pragma unroll
      for (int i = 0; i < 4; ++i) cv[i] = Cs[(ty * 4 + i) * 65 + n];
#pragma unroll
      for (int j = 0; j < 4; ++j) sv[j] = Ss[n * 64 + tx * 4 + j];
#pragma unroll
      for (int i = 0; i < 4; ++i)
#pragma unroll
        for (int j = 0; j < 4; ++j) y[i][j] = fmaf(cv[i], sv[j], y[i][j]);
    }
  }
#pragma unroll
  for (int i = 0; i < 4; ++i) {
    int tl = ty * 4 + i;
    int t = t0 + tl;
    if (t < LTOK && km[(long)b * LTOK + t]) {
      float ev = evec[tl];
      float* yp = Y + ((long)(b * LTOK + t)) * DIN + h * 64 + tx * 4;
#pragma unroll
      for (int j = 0; j < 4; ++j) yp[j] += ev * y[i][j];
    }
  }
}

// ---------------- y(+D*x) + gate silu(z) + RMSNorm — gathered rows only ----------------
__global__ __launch_bounds__(256) void k_gaterms(float* __restrict__ Y,
                                                 const float* __restrict__ xbc,
                                                 const float* __restrict__ zx,
                                                 const float* __restrict__ Dv,
                                                 const float* __restrict__ rmsw,
                                                 const int* __restrict__ rowidx) {
  long r = rowidx[blockIdx.x];
  int tid = threadIdx.x;
  int e = tid * 4;
  int h = tid >> 4;
  float4 a = *(const float4*)(Y + r * DIN + e);
  const float4 xv = *(const float4*)(xbc + r * CDIM + e);
  const float4 zv = *(const float4*)(zx + r * EPROJ + e);
  float Dh = Dv[h];
  float y0 = a.x + Dh * xv.x, y1 = a.y + Dh * xv.y;
  float y2 = a.z + Dh * xv.z, y3 = a.w + Dh * xv.w;
  float g0 = y0 * (zv.x / (1.f + expf(-zv.x)));
  float g1 = y1 * (zv.y / (1.f + expf(-zv.y)));
  float g2 = y2 * (zv.z / (1.f + expf(-zv.z)));
  float g3 = y3 * (zv.w / (1.f + expf(-zv.w)));
  __shared__ float red[256];
  red[tid] = g0*g0 + g1*g1 + g2*g2 + g3*g3;
  __syncthreads();
  for (int st = 128; st; st >>= 1) {
    if (tid < st) red[tid] += red[tid + st];
    __syncthreads();
  }
  float scale = rsqrtf(red[0] * (1.0f / 1024.0f) + 1e-5f);
  float4 rw = *(const float4*)(rmsw + e);
  float4 o;
  o.x = g0 * scale * rw.x; o.y = g1 * scale * rw.y;
  o.z = g2 * scale * rw.z; o.w = g3 * scale * rw.w;
  *(float4*)(Y + r * DIN + e) = o;
}

// ---------------- final LayerNorm -> f32 out ----------------
__global__ __launch_bounds__(256) void k_ln(const float* __restrict__ outg,
                                            const float* __restrict__ lng,
                                            const float* __restrict__ lnb,
                                            float* __restrict__ out) {
  int r = blockIdx.x;
  int tid = threadIdx.x;
  const float2 v = *(const float2*)(outg + (long)r * DM + tid * 2);
  __shared__ float red[256];
  red[tid] = v.x + v.y;
  __syncthreads();
  for (int st = 128; st; st >>= 1) { if (tid < st) red[tid] += red[tid + st]; __syncthreads(); }
  float mu = red[0] * (1.0f / 512.0f);
  __syncthreads();
  float dx = v.x - mu, dy = v.y - mu;
  red[tid] = dx * dx + dy * dy;
  __syncthreads();
  for (int st = 128; st; st >>= 1) { if (tid < st) red[tid] += red[tid + st]; __syncthreads(); }
  float sc = rsqrtf(red[0] * (1.0f / 512.0f) + 1e-5f);
  int c = tid * 2;
  out[(long)r * DM + c]     = dx * sc * lng[c] + lnb[c];
  out[(long)r * DM + c + 1] = dy * sc * lng[c + 1] + lnb[c + 1];
}

// ---------------- launch ----------------
extern "C" void kernel_launch(void* const* d_in, const int* in_sizes, int n_in,
                              void* d_out, int out_size, void* d_ws, size_t ws_size,
                              hipStream_t stream) {
  float* ws = (float*)d_ws;
  float* out = (float*)d_out;
  int* rowidx = (int*)(ws + O_RIDX);
  int* km = (int*)(ws + O_KM);
  InPtrs ip;
  for (int i = 0; i < 14; ++i) ip.p[i] = d_in[i];

  hipLaunchKernelGGL(k_convert, dim3(1160, 14), dim3(256), 0, stream, ip, ws);
  hipLaunchKernelGGL(k_rng, dim3(16, 2), dim3(256), 0, stream, out, rowidx, km);
  hipLaunchKernelGGL(k_im2col, dim3(2048), dim3(192), 0, stream, ws + O_CX, ws + O_X3);
  hipLaunchKernelGGL(k_clsrow, dim3(2), dim3(512), 0, stream, ws + O_CLS, ws + O_H);
  // conv-embed GEMM (MFMA): (2048 x 192) @ (512 x 192)^T + bias -> H (cls-gap remap)
  hipLaunchKernelGGL(k_bgemm, dim3(4, 16, 1), dim3(256), 0, stream,
                     ws + O_X3, ws + O_CW, ws + O_H, ws + O_CB, (const int*)nullptr,
                     2048, 512, 192, 512, 1);
  // in_proj part A (xBC + dt logits): (2050 x 512) @ (1296 x 512)^T -> zx cols 1024..2320
  hipLaunchKernelGGL(k_bgemm, dim3(11, 17, 1), dim3(256), 0, stream,
                     ws + O_H, ws + O_IPW + (long)DIN * DM, ws + O_ZX + DIN,
                     (const float*)nullptr, (const int*)nullptr,
                     2050, EPROJ - DIN, 512, EPROJ, 0);
  // in_proj part B (z, gathered rows only): (514 x 512) @ (1024 x 512)^T -> zx cols 0..1024
  hipLaunchKernelGGL(k_bgemm, dim3(8, 5, 1), dim3(256), 0, stream,
                     ws + O_H, ws + O_IPW, ws + O_ZX,
                     (const float*)nullptr, rowidx,
                     514, DIN, 512, EPROJ, 2);
  hipLaunchKernelGGL(k_conv1d, dim3(2050), dim3(256), 0, stream,
                     ws + O_ZX, ws + O_C1W, ws + O_C1B, ws + O_XBC);
  hipLaunchKernelGGL(k_dtda, dim3(129), dim3(256), 0, stream,
                     ws + O_ZX, ws + O_DTB, ws + O_ALOG, ws + O_DT, ws + O_LGA);
  hipLaunchKernelGGL(k_ssd1, dim3(32 * NCH), dim3(256), 0, stream,
                     ws + O_XBC, ws + O_DT, ws + O_LGA, ws + O_Y, ws + O_SL, ws + O_CLA, km);
  hipLaunchKernelGGL(k_comb, dim3(256), dim3(256), 0, stream, ws + O_SL, ws + O_CLA);
  hipLaunchKernelGGL(k_ssd3, dim3(32 * NCH), dim3(256), 0, stream,
                     ws + O_XBC, ws + O_SL, ws + O_CLA, ws + O_Y, km);
  hipLaunchKernelGGL(k_gaterms, dim3(514), dim3(256), 0, stream,
                     ws + O_Y, ws + O_XBC, ws + O_ZX, ws + O_DV, ws + O_RMSW, rowidx);
  // out_proj GEMM (MFMA, split-K=4 + atomics): (514 x 1024) @ (512 x 1024)^T -> outg
  hipLaunchKernelGGL(k_zero, dim3(257), dim3(256), 0, stream, ws + O_OUTG, 263168);
  hipLaunchKernelGGL(k_bgemm, dim3(4, 5, 4), dim3(256), 0, stream,
                     ws + O_Y, ws + O_OPW, ws + O_OUTG, (const float*)nullptr, rowidx,
                     514, 512, 1024, 512, 0);
  hipLaunchKernelGGL(k_ln, dim3(514), dim3(256), 0, stream,
                     ws + O_OUTG, ws + O_LNG, ws + O_LNB, out);
}

// Round 13
// 252.068 us; speedup vs baseline: 1.0975x; 1.0975x over previous
//
#include <hip/hip_runtime.h>
#include <hip/hip_bf16.h>
#include <stdint.h>

// ---------------- problem constants ----------------
#define LTOK  1025      // 1024 body + 1 cls
#define NROWS 2050      // B * LTOK
#define DM    512
#define DIN   1024
#define DST   128
#define NHEAD 16
#define HDIM  64
#define CDIM  1280      // DIN + 2*DST
#define EPROJ 2320      // 2*DIN + 2*DST + NHEAD
#define QC    64        // SSD chunk length
#define NCH   17        // ceil(1025/64)

// ---------------- workspace layout (float offsets), ~65.0 MB ----------------
#define O_RIDX   0          // int32 x 514 (reserve 1024)
#define O_CB     1024
#define O_CLS    1536
#define O_C1B    2048
#define O_DTB    3328
#define O_ALOG   3344
#define O_DV     3360
#define O_RMSW   3376
#define O_LNG    4400
#define O_LNB    4912
#define O_CW     5440
#define O_IPW    103744
#define O_OPW    1291584
#define O_C1W    1815872
#define O_CX     1820992
#define O_ZX     1952064
#define O_XBC    6708064
#define O_DT     9332064
#define O_LGA    9364864    // log(dA) = dt * (-exp(A_log))
#define O_Y      9397664    // 2,099,200 floats; overlays H and X3 (dead after in_proj)
#define O_H      9397664    // 1,049,600
#define O_X3     10447264   // 393,216
#define O_OUTG   11496864   // 263,168
#define O_SL     11760032   // chunk states: 32*17*8192 (S_loc, then in-place S_start)
#define O_CLA    16216480   // within-chunk cumsum logdA: 32*17*64 -> ends 16,251,296

// ---------------- output layout (FLOAT32 elements) ----------------
#define OO_MASK 263168
#define OO_IDR  265216
#define OO_IDK  267264

typedef __attribute__((ext_vector_type(8))) short short8;
typedef __attribute__((ext_vector_type(4))) short shortx4;
typedef __attribute__((ext_vector_type(4))) float floatx4;

__device__ __forceinline__ short f2bs(float f) {
  union { float f; uint32_t u; } v; v.f = f;
  uint32_t r = (v.u + 0x7FFFu + ((v.u >> 16) & 1u)) >> 16;
  return (short)r;
}

struct InPtrs { const void* p[14]; };

// ---------------- input dtype detect + convert to f32 (slice 14 zeroes OUTG) ----------------
__device__ int detect_is_f32(const uint32_t* w, int nelem) {
  int nw = nelem / 2; if (nw > 16) nw = 16;
  int insane = 0, lozero = 0, anynz = 0;
  for (int i = 0; i < nw; ++i) {
    uint32_t word = w[i];
    if (word != 0u) anynz = 1;
    uint32_t lo = word & 0xffffu;
    if (lo == 0u) { lozero++; continue; }
    float v = __uint_as_float(lo << 16);
    float a = fabsf(v);
    if (!(a >= 1e-8f && a <= 1e4f)) insane++;
  }
  if (insane >= 2) return 1;
  if (lozero == nw && anynz) return 1;
  return 0;
}

__global__ __launch_bounds__(256) void k_convert(InPtrs ptrs, float* ws) {
  static const int sizes[14] = {131072, 98304, 512, 512, 1187840, 5120, 1280,
                                16, 16, 16, 1024, 524288, 512, 512};
  static const int offs[14]  = {O_CX, O_CW, O_CB, O_CLS, O_IPW, O_C1W, O_C1B,
                                O_DTB, O_ALOG, O_DV, O_RMSW, O_OPW, O_LNG, O_LNB};
  int t = blockIdx.y;
  int base = (blockIdx.x * 256 + threadIdx.x) * 4;
  if (t == 14) {                                   // fused: zero OUTG for split-K atomics
    if (base < 263168)
      *(float4*)(ws + O_OUTG + base) = make_float4(0.f, 0.f, 0.f, 0.f);
    return;
  }
  int n = sizes[t];
  const uint32_t* w = (const uint32_t*)ptrs.p[t];
  __shared__ int sf;
  if (threadIdx.x == 0) sf = detect_is_f32(w, n);
  __syncthreads();
  if (base >= n) return;
  float* dst = ws + offs[t];
  if (sf) {
    *(float4*)(dst + base) = *(const float4*)((const float*)w + base);
  } else {
    const uint32_t* s = w + (base >> 1);
    uint32_t w0 = s[0], w1 = s[1];
    float4 o;
    o.x = __uint_as_float((w0 & 0xffffu) << 16);
    o.y = __uint_as_float(w0 & 0xffff0000u);
    o.z = __uint_as_float((w1 & 0xffffu) << 16);
    o.w = __uint_as_float(w1 & 0xffff0000u);
    *(float4*)(dst + base) = o;
  }
}

// ---------------- threefry2x32 (JAX-compatible) ----------------
__device__ __forceinline__ uint32_t rotl32(uint32_t v, int d) {
  return (v << d) | (v >> (32 - d));
}
__device__ void threefry2x32(uint32_t k0, uint32_t k1, uint32_t c0, uint32_t c1,
                             uint32_t& o0, uint32_t& o1) {
  uint32_t ks0 = k0, ks1 = k1, ks2 = 0x1BD11BDAu ^ k0 ^ k1;
  uint32_t x0 = c0 + ks0, x1 = c1 + ks1;
#define TF_R4(a,b,c,d) \
  x0 += x1; x1 = rotl32(x1,a); x1 ^= x0; \
  x0 += x1; x1 = rotl32(x1,b); x1 ^= x0; \
  x0 += x1; x1 = rotl32(x1,c); x1 ^= x0; \
  x0 += x1; x1 = rotl32(x1,d); x1 ^= x0;
  TF_R4(13,15,26,6)  x0 += ks1; x1 += ks2 + 1u;
  TF_R4(17,29,16,24) x0 += ks2; x1 += ks0 + 2u;
  TF_R4(13,15,26,6)  x0 += ks0; x1 += ks1 + 3u;
  TF_R4(17,29,16,24) x0 += ks1; x1 += ks2 + 4u;
  TF_R4(13,15,26,6)  x0 += ks2; x1 += ks0 + 5u;
#undef TF_R4
  o0 = x0; o1 = x1;
}

// RNG + stable argsort ranks. grid (16, 2); 64 targets/block,
// 4 threads/target scanning 256-element quarters, shfl-combined.
__global__ __launch_bounds__(256) void k_rng(float* out, int* rowidx) {
  int b = blockIdx.y;
  int seg = blockIdx.x;
  int tid = threadIdx.x;
  __shared__ float vals[1024];
  uint32_t fk0, fk1;
  threefry2x32(0u, 0u, 0u, 1u, fk0, fk1);          // fold_in(key(0), 1)
#pragma unroll
  for (int k = 0; k < 4; ++k) {
    int i = tid + k * 256;
    uint32_t o0, o1;
    threefry2x32(fk0, fk1, 0u, (uint32_t)(b * 1024 + i), o0, o1);
    uint32_t bits = o0 ^ o1;
    vals[i] = __uint_as_float((bits >> 9) | 0x3f800000u) - 1.0f;
  }
  __syncthreads();
  int tg = seg * 64 + (tid >> 2);      // target index
  int qq = tid & 3;                    // quarter
  float v = vals[tg];
  int r = 0;
  int j0 = qq * 256;
  for (int it = 0; it < 256; ++it) {
    int j = j0 + ((it + qq * 8) & 255);
    float vj = vals[j];
    r += (vj < v || (vj == v && j < tg)) ? 1 : 0;
  }
  r += __shfl_xor(r, 1, 64);
  r += __shfl_xor(r, 2, 64);
  if (qq == 0) {
    out[OO_IDR + b * 1024 + tg] = (float)r;
    out[OO_MASK + b * 1024 + tg] = (r < 256) ? 0.0f : 1.0f;
    if (r < 256) {
      out[OO_IDK + b * 256 + r] = (float)tg;
      rowidx[b * 257 + r] = b * LTOK + tg;
    }
    if (tg == 0) rowidx[b * 257 + 256] = b * LTOK + 1024;
  }
}

// ---------------- im2col for conv-embed (+ fused cls row write) ----------------
__global__ void k_im2col(const float* __restrict__ x, float* __restrict__ X3,
                         const float* __restrict__ cls, float* __restrict__ h) {
  int r = blockIdx.x;
  int j = threadIdx.x;
  if (r >= 2048) {                       // fused k_clsrow: blocks 2048, 2049
    int b = r - 2048;
    for (int c = j; c < DM; c += 192)
      h[((long)(b * LTOK + 1024)) * DM + c] = cls[c];
    return;
  }
  int b = r >> 10, t = r & 1023;
  if (j < 192) {
    int i = j / 3, k = j % 3;
    int tt = t + k - 1;
    float v = (tt >= 0 && tt < 1024) ? x[((long)(b * 1024 + tt)) * 64 + i] : 0.f;
    X3[(long)r * 192 + j] = v;
  }
}

// ---------------- MFMA bf16 GEMM: C = A @ Bw^T (+bias), f32 in/out ----------------
// 128x128 tile, double-buffered LDS, optional split-K (atomicAdd epilogue, C pre-zeroed).
__global__ __launch_bounds__(256) void k_bgemm(
    const float* __restrict__ A, const float* __restrict__ Bw,
    float* __restrict__ C, const float* __restrict__ bias,
    const int* __restrict__ rowmap, int M, int N, int K, int ldc, int cmode) {
  __shared__ __align__(16) short sA[2][128 * 40];
  __shared__ __align__(16) short sB[2][128 * 40];
  int tid = threadIdx.x;
  int lane = tid & 63, w = tid >> 6;
  int lm = lane & 15, q = lane >> 4;
  int wm = (w >> 1) * 64, wn = (w & 1) * 64;
  int bm = blockIdx.y * 128, bn = blockIdx.x * 128;
  int gz = gridDim.z;
  int Ks = K / gz;
  int kbase = blockIdx.z * Ks;
  int nk = Ks >> 5;

  int srow[4], scol[4];
  long aoff[4]; bool aok[4]; long boff[4]; bool bok[4];
#pragma unroll
  for (int it = 0; it < 4; ++it) {
    int e4 = (tid + it * 256) * 4;
    srow[it] = e4 >> 5; scol[it] = e4 & 31;
    int gm = bm + srow[it];
    aok[it] = gm < M;
    aoff[it] = aok[it] ? (long)(rowmap ? rowmap[gm] : gm) * K : 0;
    int gn = bn + srow[it];
    bok[it] = gn < N;
    boff[it] = bok[it] ? (long)gn * K : 0;
  }

  auto gload = [&](int kt, float4* va, float4* vb) {
    int kc = kbase + kt * 32;
#pragma unroll
    for (int it = 0; it < 4; ++it) {
      va[it] = aok[it] ? *(const float4*)(A + aoff[it] + kc + scol[it])
                       : make_float4(0.f, 0.f, 0.f, 0.f);
      vb[it] = bok[it] ? *(const float4*)(Bw + boff[it] + kc + scol[it])
                       : make_float4(0.f, 0.f, 0.f, 0.f);
    }
  };
  auto sstore = [&](int buf, const float4* va, const float4* vb) {
#pragma unroll
    for (int it = 0; it < 4; ++it) {
      *(shortx4*)&sA[buf][srow[it] * 40 + scol[it]] =
          shortx4{f2bs(va[it].x), f2bs(va[it].y), f2bs(va[it].z), f2bs(va[it].w)};
      *(shortx4*)&sB[buf][srow[it] * 40 + scol[it]] =
          shortx4{f2bs(vb[it].x), f2bs(vb[it].y), f2bs(vb[it].z), f2bs(vb[it].w)};
    }
  };

  floatx4 acc[4][4] = {};
  float4 va[4], vb[4], na[4], nb[4];

  gload(0, va, vb);
  sstore(0, va, vb);
  for (int kt = 0; kt < nk; ++kt) {
    int cur = kt & 1;
    if (kt + 1 < nk) gload(kt + 1, na, nb);
    __syncthreads();
    short8 afrag[4], bfrag[4];
#pragma unroll
    for (int i = 0; i < 4; ++i)
      afrag[i] = *(const short8*)&sA[cur][(wm + i * 16 + lm) * 40 + q * 8];
#pragma unroll
    for (int j = 0; j < 4; ++j)
      bfrag[j] = *(const short8*)&sB[cur][(wn + j * 16 + lm) * 40 + q * 8];
#pragma unroll
    for (int i = 0; i < 4; ++i)
#pragma unroll
      for (int j = 0; j < 4; ++j)
        acc[i][j] = __builtin_amdgcn_mfma_f32_16x16x32_bf16(afrag[i], bfrag[j], acc[i][j], 0, 0, 0);
    if (kt + 1 < nk) sstore(1 - cur, na, nb);
  }

#pragma unroll
  for (int i = 0; i < 4; ++i) {
    int rowl = wm + i * 16 + q * 4;
#pragma unroll
    for (int reg = 0; reg < 4; ++reg) {
      int r = bm + rowl + reg;
      if (r >= M) continue;
      long crow = cmode ? (long)((r >> 10) * LTOK + (r & 1023)) : (long)r;
#pragma unroll
      for (int j = 0; j < 4; ++j) {
        int ccol = bn + wn + j * 16 + lm;
        if (ccol < N) {
          float v = acc[i][j][reg];
          if (gz > 1) {
            atomicAdd(&C[crow * ldc + ccol], v);
          } else {
            if (bias) v += bias[ccol];
            C[crow * ldc + ccol] = v;
          }
        }
      }
    }
  }
}

// ---------------- depthwise causal conv(4) + silu ----------------
__global__ __launch_bounds__(256) void k_conv1d(const float* __restrict__ zx,
                                                const float* __restrict__ w,
                                                const float* __restrict__ bias,
                                                float* __restrict__ xbc) {
  long r = blockIdx.x;
  int b = (int)(r / LTOK), t = (int)(r % LTOK);
  for (int c = threadIdx.x; c < CDIM; c += 256) {
    float acc = bias[c];
    const float* wp = w + c * 4;
#pragma unroll
    for (int k = 0; k < 4; ++k) {
      int tt = t - 3 + k;
      if (tt >= 0)
        acc = fmaf(wp[k], zx[((long)(b * LTOK + tt)) * EPROJ + DIN + c], acc);
    }
    xbc[r * CDIM + c] = acc / (1.f + expf(-acc));
  }
}

// ---------------- dt = softplus(logit + bias), lga = dt * -exp(A_log) ----------------
__global__ void k_dtda(const float* __restrict__ zx, const float* __restrict__ dtb,
                       const float* __restrict__ alog, float* __restrict__ dt,
                       float* __restrict__ lga) {
  int idx = blockIdx.x * 256 + threadIdx.x;
  if (idx >= NROWS * NHEAD) return;
  int r = idx >> 4, h = idx & 15;
  float xv = zx[(long)r * EPROJ + (EPROJ - NHEAD) + h] + dtb[h];
  float dtv = (xv > 20.f) ? xv : log1pf(expf(xv));
  dt[idx] = dtv;
  lga[idx] = dtv * (-expf(alog[h]));
}

// ---------------- SSD phase 1 (MFMA bf16): per (b,h,chunk) intra-chunk work ----------------
__global__ __launch_bounds__(256) void k_ssd1(const float* __restrict__ xbc,
                                              const float* __restrict__ dt,
                                              const float* __restrict__ lga,
                                              float* __restrict__ Y,
                                              float* __restrict__ SL,
                                              float* __restrict__ CLA) {
  int blk = blockIdx.x;
  int c = blk % NCH;
  int hh = blk / NCH;            // h + 16*b
  int h = hh & 15, b = hh >> 4;
  int tid = threadIdx.x;
  int lane = tid & 63, w = tid >> 6;
  int lm = lane & 15, q = lane >> 4;

  __shared__ __align__(16) short sB[64 * 136];
  __shared__ __align__(16) short sC[64 * 136];
  __shared__ __align__(16) short sBT[128 * 72];
  __shared__ __align__(16) short sXT[64 * 72];
  __shared__ __align__(16) short sM[64 * 72];
  __shared__ float dtw[64], clA[64], wwv[64];

  int t0 = c * QC;
  const float* base = xbc + (long)b * LTOK * CDIM;

  if (tid < 64) {
    int t = t0 + tid;
    dtw[tid] = (t < LTOK) ? dt[((long)(b * LTOK + t)) * NHEAD + h] : 0.f;
    clA[tid] = (t < LTOK) ? lga[((long)(b * LTOK + t)) * NHEAD + h] : 0.f;
  }
  __syncthreads();
  if (tid == 0) {
    float s = 0.f;
    for (int i = 0; i < 64; ++i) { s += clA[i]; clA[i] = s; }
  }
  __syncthreads();
  float clEnd = clA[63];
  if (tid < 64) {
    wwv[tid] = __expf(clEnd - clA[tid]) * dtw[tid];
    CLA[(long)blk * 64 + tid] = clA[tid];
  }
  __syncthreads();

#pragma unroll
  for (int k = 0; k < 8; ++k) {
    int e4 = (tid + k * 256) * 4;
    int row = e4 >> 7, col = e4 & 127;
    int t = t0 + row;
    float4 bv = make_float4(0.f,0.f,0.f,0.f), cv = make_float4(0.f,0.f,0.f,0.f);
    if (t < LTOK) {
      const float* rp = base + (long)t * CDIM;
      bv = *(const float4*)(rp + DIN + col);
      cv = *(const float4*)(rp + DIN + DST + col);
    }
    float wv = wwv[row];
    sB[row*136+col]=f2bs(bv.x); sB[row*136+col+1]=f2bs(bv.y);
    sB[row*136+col+2]=f2bs(bv.z); sB[row*136+col+3]=f2bs(bv.w);
    sC[row*136+col]=f2bs(cv.x); sC[row*136+col+1]=f2bs(cv.y);
    sC[row*136+col+2]=f2bs(cv.z); sC[row*136+col+3]=f2bs(cv.w);
    sBT[(col  )*72+row]=f2bs(bv.x*wv); sBT[(col+1)*72+row]=f2bs(bv.y*wv);
    sBT[(col+2)*72+row]=f2bs(bv.z*wv); sBT[(col+3)*72+row]=f2bs(bv.w*wv);
  }
#pragma unroll
  for (int k = 0; k < 4; ++k) {
    int e4 = (tid + k * 256) * 4;
    int row = e4 >> 6, col = e4 & 63;
    int t = t0 + row;
    float4 xv = make_float4(0.f,0.f,0.f,0.f);
    if (t < LTOK) xv = *(const float4*)(base + (long)t * CDIM + h * 64 + col);
    sXT[(col  )*72+row]=f2bs(xv.x); sXT[(col+1)*72+row]=f2bs(xv.y);
    sXT[(col+2)*72+row]=f2bs(xv.z); sXT[(col+3)*72+row]=f2bs(xv.w);
  }
  __syncthreads();

  floatx4 g[4] = {};
#pragma unroll
  for (int kb = 0; kb < 4; ++kb) {
    short8 a = *(const short8*)&sC[(w*16 + lm)*136 + kb*32 + q*8];
#pragma unroll
    for (int ct = 0; ct < 4; ++ct) {
      short8 bb = *(const short8*)&sB[(ct*16 + lm)*136 + kb*32 + q*8];
      g[ct] = __builtin_amdgcn_mfma_f32_16x16x32_bf16(a, bb, g[ct], 0, 0, 0);
    }
  }
#pragma unroll
  for (int ct = 0; ct < 4; ++ct) {
    int tp = ct*16 + lm;
#pragma unroll
    for (int reg = 0; reg < 4; ++reg) {
      int tl = w*16 + q*4 + reg;
      float m = 0.f;
      if (tp <= tl) m = g[ct][reg] * __expf(clA[tl] - clA[tp]) * dtw[tp];
      sM[tl*72 + tp] = f2bs(m);
    }
  }
  __syncthreads();

  floatx4 y[4] = {};
#pragma unroll
  for (int kb = 0; kb < 2; ++kb) {
    short8 a = *(const short8*)&sM[(w*16 + lm)*72 + kb*32 + q*8];
#pragma unroll
    for (int ct = 0; ct < 4; ++ct) {
      short8 bb = *(const short8*)&sXT[(ct*16 + lm)*72 + kb*32 + q*8];
      y[ct] = __builtin_amdgcn_mfma_f32_16x16x32_bf16(a, bb, y[ct], 0, 0, 0);
    }
  }
#pragma unroll
  for (int ct = 0; ct < 4; ++ct) {
    int p = ct*16 + lm;
#pragma unroll
    for (int reg = 0; reg < 4; ++reg) {
      int t = t0 + w*16 + q*4 + reg;
      if (t < LTOK)
        Y[((long)(b * LTOK + t)) * DIN + h * 64 + p] = y[ct][reg];
    }
  }

  floatx4 s[2][4] = {};
#pragma unroll
  for (int kb = 0; kb < 2; ++kb) {
    short8 bfr[4];
#pragma unroll
    for (int ct = 0; ct < 4; ++ct)
      bfr[ct] = *(const short8*)&sXT[(ct*16 + lm)*72 + kb*32 + q*8];
#pragma unroll
    for (int nt = 0; nt < 2; ++nt) {
      short8 a = *(const short8*)&sBT[((w*2+nt)*16 + lm)*72 + kb*32 + q*8];
#pragma unroll
      for (int ct = 0; ct < 4; ++ct)
        s[nt][ct] = __builtin_amdgcn_mfma_f32_16x16x32_bf16(a, bfr[ct], s[nt][ct], 0, 0, 0);
    }
  }
  float* slp = SL + (long)blk * 8192;
#pragma unroll
  for (int nt = 0; nt < 2; ++nt)
#pragma unroll
    for (int ct = 0; ct < 4; ++ct)
#pragma unroll
      for (int reg = 0; reg < 4; ++reg) {
        int n = (w*2+nt)*16 + q*4 + reg;
        int p = ct*16 + lm;
        slp[n*64 + p] = s[nt][ct][reg];
      }
}

// ---------------- SSD phase 2a: in-place sequential combine over chunks ----------------
__global__ __launch_bounds__(256) void k_comb(float* __restrict__ SL,
                                              const float* __restrict__ CLA) {
  int bx = blockIdx.x;
  int piece = bx & 7;
  int hh = bx >> 3;
  int off = piece * 1024 + threadIdx.x * 4;
  float4 s = make_float4(0.f, 0.f, 0.f, 0.f);
  for (int c = 0; c < NCH; ++c) {
    long cb = (long)(hh * NCH + c);
    float* p = SL + cb * 8192 + off;
    float P = __expf(CLA[cb * 64 + 63]);
    float4 tmp = *(float4*)p;
    *(float4*)p = s;
    s.x = fmaf(P, s.x, tmp.x);
    s.y = fmaf(P, s.y, tmp.y);
    s.z = fmaf(P, s.z, tmp.z);
    s.w = fmaf(P, s.w, tmp.w);
  }
}

// ---------------- SSD phase 2b: Y += evec[t] * C_t . S_start  (fully parallel) ----------------
__global__ __launch_bounds__(256) void k_ssd3(const float* __restrict__ xbc,
                                              const float* __restrict__ SL,
                                              const float* __restrict__ CLA,
                                              float* __restrict__ Y) {
  int blk = blockIdx.x;
  int c = blk % NCH;
  int hh = blk / NCH;
  int h = hh & 15, b = hh >> 4;
  int tid = threadIdx.x;
  int tx = tid & 15, ty = tid >> 4;

  __shared__ float Cs[64 * 65];
  __shared__ float Ss[64 * 64];
  __shared__ float evec[64];

  int t0 = c * QC;
  const float* base = xbc + (long)b * LTOK * CDIM;
  const float* slp = SL + (long)blk * 8192;
  if (tid < 64) evec[tid] = __expf(CLA[(long)blk * 64 + tid]);

  float y[4][4] = {};
#pragma unroll
  for (int half = 0; half < 2; ++half) {
    int n0 = half * 64;
    __syncthreads();
#pragma unroll
    for (int k = 0; k < 16; ++k) {
      int e = tid + k * 256;
      int row = e >> 6, col = e & 63;
      int t = t0 + row;
      Cs[row * 65 + col] = (t < LTOK) ? base[(long)t * CDIM + DIN + DST + n0 + col] : 0.f;
    }
#pragma unroll
    for (int k = 0; k < 4; ++k) {
      int e = (tid + k * 256) * 4;
      *(float4*)(Ss + e) = *(const float4*)(slp + n0 * 64 + e);
    }
    __syncthreads();
    for (int n = 0; n < 64; ++n) {
      float cv[4], sv[4];
#pragma unroll
      for (int i = 0; i < 4; ++i) cv[i] = Cs[(ty * 4 + i) * 65 + n];
#pragma unroll
      for (int j = 0; j < 4; ++j) sv[j] = Ss[n * 64 + tx * 4 + j];
#pragma unroll
      for (int i = 0; i < 4; ++i)
#pragma unroll
        for (int j = 0; j < 4; ++j) y[i][j] = fmaf(cv[i], sv[j], y[i][j]);
    }
  }
#pragma unroll
  for (int i = 0; i < 4; ++i) {
    int tl = ty * 4 + i;
    int t = t0 + tl;
    if (t < LTOK) {
      float ev = evec[tl];
      float* yp = Y + ((long)(b * LTOK + t)) * DIN + h * 64 + tx * 4;
#pragma unroll
      for (int j = 0; j < 4; ++j) yp[j] += ev * y[i][j];
    }
  }
}

// ---------------- y(+D*x) + gate silu(z) + RMSNorm, in place on Y ----------------
__global__ __launch_bounds__(256) void k_gaterms(float* __restrict__ Y,
                                                 const float* __restrict__ xbc,
                                                 const float* __restrict__ zx,
                                                 const float* __restrict__ Dv,
                                                 const float* __restrict__ rmsw) {
  long r = blockIdx.x;
  int tid = threadIdx.x;
  int e = tid * 4;
  int h = tid >> 4;
  float4 a = *(const float4*)(Y + r * DIN + e);
  const float4 xv = *(const float4*)(xbc + r * CDIM + e);
  const float4 zv = *(const float4*)(zx + r * EPROJ + e);
  float Dh = Dv[h];
  float y0 = a.x + Dh * xv.x, y1 = a.y + Dh * xv.y;
  float y2 = a.z + Dh * xv.z, y3 = a.w + Dh * xv.w;
  float g0 = y0 * (zv.x / (1.f + expf(-zv.x)));
  float g1 = y1 * (zv.y / (1.f + expf(-zv.y)));
  float g2 = y2 * (zv.z / (1.f + expf(-zv.z)));
  float g3 = y3 * (zv.w / (1.f + expf(-zv.w)));
  __shared__ float red[256];
  red[tid] = g0*g0 + g1*g1 + g2*g2 + g3*g3;
  __syncthreads();
  for (int st = 128; st; st >>= 1) {
    if (tid < st) red[tid] += red[tid + st];
    __syncthreads();
  }
  float scale = rsqrtf(red[0] * (1.0f / 1024.0f) + 1e-5f);
  float4 rw = *(const float4*)(rmsw + e);
  float4 o;
  o.x = g0 * scale * rw.x; o.y = g1 * scale * rw.y;
  o.z = g2 * scale * rw.z; o.w = g3 * scale * rw.w;
  *(float4*)(Y + r * DIN + e) = o;
}

// ---------------- final LayerNorm -> f32 out ----------------
__global__ __launch_bounds__(256) void k_ln(const float* __restrict__ outg,
                                            const float* __restrict__ lng,
                                            const float* __restrict__ lnb,
                                            float* __restrict__ out) {
  int r = blockIdx.x;
  int tid = threadIdx.x;
  const float2 v = *(const float2*)(outg + (long)r * DM + tid * 2);
  __shared__ float red[256];
  red[tid] = v.x + v.y;
  __syncthreads();
  for (int st = 128; st; st >>= 1) { if (tid < st) red[tid] += red[tid + st]; __syncthreads(); }
  float mu = red[0] * (1.0f / 512.0f);
  __syncthreads();
  float dx = v.x - mu, dy = v.y - mu;
  red[tid] = dx * dx + dy * dy;
  __syncthreads();
  for (int st = 128; st; st >>= 1) { if (tid < st) red[tid] += red[tid + st]; __syncthreads(); }
  float sc = rsqrtf(red[0] * (1.0f / 512.0f) + 1e-5f);
  int c = tid * 2;
  out[(long)r * DM + c]     = dx * sc * lng[c] + lnb[c];
  out[(long)r * DM + c + 1] = dy * sc * lng[c + 1] + lnb[c + 1];
}

// ---------------- launch ----------------
extern "C" void kernel_launch(void* const* d_in, const int* in_sizes, int n_in,
                              void* d_out, int out_size, void* d_ws, size_t ws_size,
                              hipStream_t stream) {
  float* ws = (float*)d_ws;
  float* out = (float*)d_out;
  int* rowidx = (int*)(ws + O_RIDX);
  InPtrs ip;
  for (int i = 0; i < 14; ++i) ip.p[i] = d_in[i];

  // slice 14 zeroes OUTG (for split-K atomics) — fused into convert
  hipLaunchKernelGGL(k_convert, dim3(1160, 15), dim3(256), 0, stream, ip, ws);
  hipLaunchKernelGGL(k_rng, dim3(16, 2), dim3(256), 0, stream, out, rowidx);
  // blocks 2048/2049 write the cls rows of H (fused k_clsrow)
  hipLaunchKernelGGL(k_im2col, dim3(2050), dim3(192), 0, stream,
                     ws + O_CX, ws + O_X3, ws + O_CLS, ws + O_H);
  // conv-embed GEMM (MFMA): (2048 x 192) @ (512 x 192)^T + bias -> H (cls-gap remap)
  hipLaunchKernelGGL(k_bgemm, dim3(4, 16, 1), dim3(256), 0, stream,
                     ws + O_X3, ws + O_CW, ws + O_H, ws + O_CB, (const int*)nullptr,
                     2048, 512, 192, 512, 1);
  // in_proj GEMM (MFMA): (2050 x 512) @ (2320 x 512)^T -> zxbcdt
  hipLaunchKernelGGL(k_bgemm, dim3(19, 17, 1), dim3(256), 0, stream,
                     ws + O_H, ws + O_IPW, ws + O_ZX, (const float*)nullptr, (const int*)nullptr,
                     2050, 2320, 512, 2320, 0);
  hipLaunchKernelGGL(k_conv1d, dim3(2050), dim3(256), 0, stream,
                     ws + O_ZX, ws + O_C1W, ws + O_C1B, ws + O_XBC);
  hipLaunchKernelGGL(k_dtda, dim3(129), dim3(256), 0, stream,
                     ws + O_ZX, ws + O_DTB, ws + O_ALOG, ws + O_DT, ws + O_LGA);
  hipLaunchKernelGGL(k_ssd1, dim3(32 * NCH), dim3(256), 0, stream,
                     ws + O_XBC, ws + O_DT, ws + O_LGA, ws + O_Y, ws + O_SL, ws + O_CLA);
  hipLaunchKernelGGL(k_comb, dim3(256), dim3(256), 0, stream, ws + O_SL, ws + O_CLA);
  hipLaunchKernelGGL(k_ssd3, dim3(32 * NCH), dim3(256), 0, stream,
                     ws + O_XBC, ws + O_SL, ws + O_CLA, ws + O_Y);
  hipLaunchKernelGGL(k_gaterms, dim3(2050), dim3(256), 0, stream,
                     ws + O_Y, ws + O_XBC, ws + O_ZX, ws + O_DV, ws + O_RMSW);
  // out_proj GEMM (MFMA, split-K=4 + atomics): (514 x 1024) @ (512 x 1024)^T -> outg
  hipLaunchKernelGGL(k_bgemm, dim3(4, 5, 4), dim3(256), 0, stream,
                     ws + O_Y, ws + O_OPW, ws + O_OUTG, (const float*)nullptr, rowidx,
                     514, 512, 1024, 512, 0);
  hipLaunchKernelGGL(k_ln, dim3(514), dim3(256), 0, stream,
                     ws + O_OUTG, ws + O_LNG, ws + O_LNB, out);
}

// Round 14
// 244.544 us; speedup vs baseline: 1.1312x; 1.0308x over previous
//
#include <hip/hip_runtime.h>
#include <hip/hip_bf16.h>
#include <stdint.h>

// ---------------- problem constants ----------------
#define LTOK  1025      // 1024 body + 1 cls
#define NROWS 2050      // B * LTOK
#define DM    512
#define DIN   1024
#define DST   128
#define NHEAD 16
#define HDIM  64
#define CDIM  1280      // DIN + 2*DST
#define EPROJ 2320      // 2*DIN + 2*DST + NHEAD
#define QC    64        // SSD chunk length
#define NCH   17        // ceil(1025/64)

// ---------------- workspace layout (float offsets), ~65.0 MB ----------------
#define O_RIDX   0          // int32 x 514 (reserve 1024)
#define O_CB     1024
#define O_CLS    1536
#define O_C1B    2048
#define O_DTB    3328
#define O_ALOG   3344
#define O_DV     3360
#define O_RMSW   3376
#define O_LNG    4400
#define O_LNB    4912
#define O_CW     5440       // bf16 (ushort) from this round
#define O_IPW    103744     // bf16 (ushort)
#define O_OPW    1291584    // bf16 (ushort)
#define O_C1W    1815872
#define O_CX     1820992
#define O_ZX     1952064
#define O_XBC    6708064
#define O_DT     9332064
#define O_LGA    9364864    // log(dA) = dt * (-exp(A_log))
#define O_Y      9397664    // 2,099,200 floats; overlays H and X3 (dead after in_proj)
#define O_H      9397664    // 1,049,600
#define O_X3     10447264   // 393,216
#define O_OUTG   11496864   // 263,168
#define O_SL     11760032   // chunk states: 32*17*8192 (S_loc, then in-place S_start)
#define O_CLA    16216480   // within-chunk cumsum logdA: 32*17*64 -> ends 16,251,296

// ---------------- output layout (FLOAT32 elements) ----------------
#define OO_MASK 263168
#define OO_IDR  265216
#define OO_IDK  267264

typedef __attribute__((ext_vector_type(8))) short short8;
typedef __attribute__((ext_vector_type(4))) short shortx4;
typedef __attribute__((ext_vector_type(4))) float floatx4;

__device__ __forceinline__ short f2bs(float f) {
  union { float f; uint32_t u; } v; v.f = f;
  uint32_t r = (v.u + 0x7FFFu + ((v.u >> 16) & 1u)) >> 16;
  return (short)r;
}

struct InPtrs { const void* p[14]; };

// ---------------- threefry2x32 (JAX-compatible) ----------------
__device__ __forceinline__ uint32_t rotl32(uint32_t v, int d) {
  return (v << d) | (v >> (32 - d));
}
__device__ void threefry2x32(uint32_t k0, uint32_t k1, uint32_t c0, uint32_t c1,
                             uint32_t& o0, uint32_t& o1) {
  uint32_t ks0 = k0, ks1 = k1, ks2 = 0x1BD11BDAu ^ k0 ^ k1;
  uint32_t x0 = c0 + ks0, x1 = c1 + ks1;
#define TF_R4(a,b,c,d) \
  x0 += x1; x1 = rotl32(x1,a); x1 ^= x0; \
  x0 += x1; x1 = rotl32(x1,b); x1 ^= x0; \
  x0 += x1; x1 = rotl32(x1,c); x1 ^= x0; \
  x0 += x1; x1 = rotl32(x1,d); x1 ^= x0;
  TF_R4(13,15,26,6)  x0 += ks1; x1 += ks2 + 1u;
  TF_R4(17,29,16,24) x0 += ks2; x1 += ks0 + 2u;
  TF_R4(13,15,26,6)  x0 += ks0; x1 += ks1 + 3u;
  TF_R4(17,29,16,24) x0 += ks1; x1 += ks2 + 4u;
  TF_R4(13,15,26,6)  x0 += ks2; x1 += ks0 + 5u;
#undef TF_R4
  o0 = x0; o1 = x1;
}

// ---------------- input dtype detect ----------------
__device__ int detect_is_f32(const uint32_t* w, int nelem) {
  int nw = nelem / 2; if (nw > 16) nw = 16;
  int insane = 0, lozero = 0, anynz = 0;
  for (int i = 0; i < nw; ++i) {
    uint32_t word = w[i];
    if (word != 0u) anynz = 1;
    uint32_t lo = word & 0xffffu;
    if (lo == 0u) { lozero++; continue; }
    float v = __uint_as_float(lo << 16);
    float a = fabsf(v);
    if (!(a >= 1e-8f && a <= 1e4f)) insane++;
  }
  if (insane >= 2) return 1;
  if (lozero == nw && anynz) return 1;
  return 0;
}

// ---------------- convert + OUTG-zero + RNG (fused) ----------------
// Slices 0..13: input conversion. Weight slices 1 (CW), 4 (IPW), 11 (OPW) are
// written as bf16 (ushort) — GEMM B operands read them directly.
// Slice 14: blocks 0..256 zero OUTG; blocks 512..543 run the RNG/argsort.
__global__ __launch_bounds__(256) void k_convert(InPtrs ptrs, float* ws,
                                                 float* out, int* rowidx) {
  static const int sizes[14] = {131072, 98304, 512, 512, 1187840, 5120, 1280,
                                16, 16, 16, 1024, 524288, 512, 512};
  static const int offs[14]  = {O_CX, O_CW, O_CB, O_CLS, O_IPW, O_C1W, O_C1B,
                                O_DTB, O_ALOG, O_DV, O_RMSW, O_OPW, O_LNG, O_LNB};
  static const int isbf[14]  = {0,1,0,0,1,0,0,0,0,0,0,1,0,0};
  int t = blockIdx.y;
  int tid = threadIdx.x;

  if (t == 14) {
    int bx = blockIdx.x;
    if (bx < 257) {                                 // zero OUTG for split-K atomics
      int base = (bx * 256 + tid) * 4;
      if (base < 263168)
        *(float4*)(ws + O_OUTG + base) = make_float4(0.f, 0.f, 0.f, 0.f);
      return;
    }
    if (bx < 512 || bx >= 544) return;
    // ---- RNG + stable argsort (bx-512 = seg + 16*b) ----
    int rb = bx - 512;
    int seg = rb & 15, b = rb >> 4;
    __shared__ float vals[1024];
    uint32_t fk0, fk1;
    threefry2x32(0u, 0u, 0u, 1u, fk0, fk1);         // fold_in(key(0), 1)
#pragma unroll
    for (int k = 0; k < 4; ++k) {
      int i = tid + k * 256;
      uint32_t o0, o1;
      threefry2x32(fk0, fk1, 0u, (uint32_t)(b * 1024 + i), o0, o1);
      uint32_t bits = o0 ^ o1;
      vals[i] = __uint_as_float((bits >> 9) | 0x3f800000u) - 1.0f;
    }
    __syncthreads();
    int tg = seg * 64 + (tid >> 2);
    int qq = tid & 3;
    float v = vals[tg];
    int r = 0;
    int j0 = qq * 256;
    for (int it = 0; it < 256; ++it) {
      int j = j0 + ((it + qq * 8) & 255);
      float vj = vals[j];
      r += (vj < v || (vj == v && j < tg)) ? 1 : 0;
    }
    r += __shfl_xor(r, 1, 64);
    r += __shfl_xor(r, 2, 64);
    if (qq == 0) {
      out[OO_IDR + b * 1024 + tg] = (float)r;
      out[OO_MASK + b * 1024 + tg] = (r < 256) ? 0.0f : 1.0f;
      if (r < 256) {
        out[OO_IDK + b * 256 + r] = (float)tg;
        rowidx[b * 257 + r] = b * LTOK + tg;
      }
      if (tg == 0) rowidx[b * 257 + 256] = b * LTOK + 1024;
    }
    return;
  }

  int n = sizes[t];
  const uint32_t* w = (const uint32_t*)ptrs.p[t];
  __shared__ int sf;
  if (tid == 0) sf = detect_is_f32(w, n);
  __syncthreads();
  int base = (blockIdx.x * 256 + tid) * 4;
  if (base >= n) return;
  if (isbf[t]) {                                    // write bf16 (ushort)
    ushort4 o;
    if (sf) {
      const float4 vv = *(const float4*)((const float*)w + base);
      o.x = (uint16_t)f2bs(vv.x); o.y = (uint16_t)f2bs(vv.y);
      o.z = (uint16_t)f2bs(vv.z); o.w = (uint16_t)f2bs(vv.w);
    } else {
      const uint32_t* s = w + (base >> 1);
      uint32_t w0 = s[0], w1 = s[1];
      o.x = (uint16_t)(w0 & 0xffffu); o.y = (uint16_t)(w0 >> 16);
      o.z = (uint16_t)(w1 & 0xffffu); o.w = (uint16_t)(w1 >> 16);
    }
    *(ushort4*)((uint16_t*)(ws + offs[t]) + base) = o;
  } else {                                          // write f32
    float* dst = ws + offs[t];
    if (sf) {
      *(float4*)(dst + base) = *(const float4*)((const float*)w + base);
    } else {
      const uint32_t* s = w + (base >> 1);
      uint32_t w0 = s[0], w1 = s[1];
      float4 o;
      o.x = __uint_as_float((w0 & 0xffffu) << 16);
      o.y = __uint_as_float(w0 & 0xffff0000u);
      o.z = __uint_as_float((w1 & 0xffffu) << 16);
      o.w = __uint_as_float(w1 & 0xffff0000u);
      *(float4*)(dst + base) = o;
    }
  }
}

// ---------------- im2col for conv-embed (+ fused cls row write) ----------------
__global__ void k_im2col(const float* __restrict__ x, float* __restrict__ X3,
                         const float* __restrict__ cls, float* __restrict__ h) {
  int r = blockIdx.x;
  int j = threadIdx.x;
  if (r >= 2048) {                       // fused k_clsrow: blocks 2048, 2049
    int b = r - 2048;
    for (int c = j; c < DM; c += 192)
      h[((long)(b * LTOK + 1024)) * DM + c] = cls[c];
    return;
  }
  int b = r >> 10, t = r & 1023;
  if (j < 192) {
    int i = j / 3, k = j % 3;
    int tt = t + k - 1;
    float v = (tt >= 0 && tt < 1024) ? x[((long)(b * 1024 + tt)) * 64 + i] : 0.f;
    X3[(long)r * 192 + j] = v;
  }
}

// ---------------- MFMA bf16 GEMM: C = A(f32) @ Bw(bf16)^T (+bias), f32 out ----------------
// 128x128 tile, double-buffered LDS, optional split-K (atomicAdd epilogue, C pre-zeroed).
__global__ __launch_bounds__(256) void k_bgemm(
    const float* __restrict__ A, const uint16_t* __restrict__ Bw,
    float* __restrict__ C, const float* __restrict__ bias,
    const int* __restrict__ rowmap, int M, int N, int K, int ldc, int cmode) {
  __shared__ __align__(16) short sA[2][128 * 40];
  __shared__ __align__(16) short sB[2][128 * 40];
  int tid = threadIdx.x;
  int lane = tid & 63, w = tid >> 6;
  int lm = lane & 15, q = lane >> 4;
  int wm = (w >> 1) * 64, wn = (w & 1) * 64;
  int bm = blockIdx.y * 128, bn = blockIdx.x * 128;
  int gz = gridDim.z;
  int Ks = K / gz;
  int kbase = blockIdx.z * Ks;
  int nk = Ks >> 5;

  int srow[4], scol[4];
  long aoff[4]; bool aok[4]; long boff[4]; bool bok[4];
#pragma unroll
  for (int it = 0; it < 4; ++it) {
    int e4 = (tid + it * 256) * 4;
    srow[it] = e4 >> 5; scol[it] = e4 & 31;
    int gm = bm + srow[it];
    aok[it] = gm < M;
    aoff[it] = aok[it] ? (long)(rowmap ? rowmap[gm] : gm) * K : 0;
    int gn = bn + srow[it];
    bok[it] = gn < N;
    boff[it] = bok[it] ? (long)gn * K : 0;
  }

  auto gload = [&](int kt, float4* va, ushort4* vb) {
    int kc = kbase + kt * 32;
#pragma unroll
    for (int it = 0; it < 4; ++it) {
      va[it] = aok[it] ? *(const float4*)(A + aoff[it] + kc + scol[it])
                       : make_float4(0.f, 0.f, 0.f, 0.f);
      if (bok[it]) vb[it] = *(const ushort4*)(Bw + boff[it] + kc + scol[it]);
      else { vb[it].x = 0; vb[it].y = 0; vb[it].z = 0; vb[it].w = 0; }
    }
  };
  auto sstore = [&](int buf, const float4* va, const ushort4* vb) {
#pragma unroll
    for (int it = 0; it < 4; ++it) {
      *(shortx4*)&sA[buf][srow[it] * 40 + scol[it]] =
          shortx4{f2bs(va[it].x), f2bs(va[it].y), f2bs(va[it].z), f2bs(va[it].w)};
      *(ushort4*)&sB[buf][srow[it] * 40 + scol[it]] = vb[it];
    }
  };

  floatx4 acc[4][4] = {};
  float4 va[4], na[4];
  ushort4 vb[4], nb[4];

  gload(0, va, vb);
  sstore(0, va, vb);
  for (int kt = 0; kt < nk; ++kt) {
    int cur = kt & 1;
    if (kt + 1 < nk) gload(kt + 1, na, nb);
    __syncthreads();
    short8 afrag[4], bfrag[4];
#pragma unroll
    for (int i = 0; i < 4; ++i)
      afrag[i] = *(const short8*)&sA[cur][(wm + i * 16 + lm) * 40 + q * 8];
#pragma unroll
    for (int j = 0; j < 4; ++j)
      bfrag[j] = *(const short8*)&sB[cur][(wn + j * 16 + lm) * 40 + q * 8];
#pragma unroll
    for (int i = 0; i < 4; ++i)
#pragma unroll
      for (int j = 0; j < 4; ++j)
        acc[i][j] = __builtin_amdgcn_mfma_f32_16x16x32_bf16(afrag[i], bfrag[j], acc[i][j], 0, 0, 0);
    if (kt + 1 < nk) sstore(1 - cur, na, nb);
  }

#pragma unroll
  for (int i = 0; i < 4; ++i) {
    int rowl = wm + i * 16 + q * 4;
#pragma unroll
    for (int reg = 0; reg < 4; ++reg) {
      int r = bm + rowl + reg;
      if (r >= M) continue;
      long crow = cmode ? (long)((r >> 10) * LTOK + (r & 1023)) : (long)r;
#pragma unroll
      for (int j = 0; j < 4; ++j) {
        int ccol = bn + wn + j * 16 + lm;
        if (ccol < N) {
          float v = acc[i][j][reg];
          if (gz > 1) {
            atomicAdd(&C[crow * ldc + ccol], v);
          } else {
            if (bias) v += bias[ccol];
            C[crow * ldc + ccol] = v;
          }
        }
      }
    }
  }
}

// ---------------- depthwise causal conv(4) + silu (+ fused dt/lga blocks) ----------------
__global__ __launch_bounds__(256) void k_conv1d(const float* __restrict__ zx,
                                                const float* __restrict__ w,
                                                const float* __restrict__ bias,
                                                float* __restrict__ xbc,
                                                const float* __restrict__ dtb,
                                                const float* __restrict__ alog,
                                                float* __restrict__ dt,
                                                float* __restrict__ lga) {
  long r = blockIdx.x;
  if (r >= NROWS) {                      // fused k_dtda: blocks 2050..2178
    int idx = (int)(r - NROWS) * 256 + threadIdx.x;
    if (idx < NROWS * NHEAD) {
      int rr = idx >> 4, h = idx & 15;
      float xv = zx[(long)rr * EPROJ + (EPROJ - NHEAD) + h] + dtb[h];
      float dtv = (xv > 20.f) ? xv : log1pf(expf(xv));
      dt[idx] = dtv;
      lga[idx] = dtv * (-expf(alog[h]));
    }
    return;
  }
  int b = (int)(r / LTOK), t = (int)(r % LTOK);
  for (int c = threadIdx.x; c < CDIM; c += 256) {
    float acc = bias[c];
    const float* wp = w + c * 4;
#pragma unroll
    for (int k = 0; k < 4; ++k) {
      int tt = t - 3 + k;
      if (tt >= 0)
        acc = fmaf(wp[k], zx[((long)(b * LTOK + tt)) * EPROJ + DIN + c], acc);
    }
    xbc[r * CDIM + c] = acc / (1.f + expf(-acc));
  }
}

// ---------------- SSD phase 1 (MFMA bf16): per (b,h,chunk) intra-chunk work ----------------
__global__ __launch_bounds__(256) void k_ssd1(const float* __restrict__ xbc,
                                              const float* __restrict__ dt,
                                              const float* __restrict__ lga,
                                              float* __restrict__ Y,
                                              float* __restrict__ SL,
                                              float* __restrict__ CLA) {
  int blk = blockIdx.x;
  int c = blk % NCH;
  int hh = blk / NCH;            // h + 16*b
  int h = hh & 15, b = hh >> 4;
  int tid = threadIdx.x;
  int lane = tid & 63, w = tid >> 6;
  int lm = lane & 15, q = lane >> 4;

  __shared__ __align__(16) short sB[64 * 136];
  __shared__ __align__(16) short sC[64 * 136];
  __shared__ __align__(16) short sBT[128 * 72];
  __shared__ __align__(16) short sXT[64 * 72];
  __shared__ __align__(16) short sM[64 * 72];
  __shared__ float dtw[64], clA[64], wwv[64];

  int t0 = c * QC;
  const float* base = xbc + (long)b * LTOK * CDIM;

  if (tid < 64) {
    int t = t0 + tid;
    dtw[tid] = (t < LTOK) ? dt[((long)(b * LTOK + t)) * NHEAD + h] : 0.f;
    clA[tid] = (t < LTOK) ? lga[((long)(b * LTOK + t)) * NHEAD + h] : 0.f;
  }
  __syncthreads();
  if (tid == 0) {
    float s = 0.f;
    for (int i = 0; i < 64; ++i) { s += clA[i]; clA[i] = s; }
  }
  __syncthreads();
  float clEnd = clA[63];
  if (tid < 64) {
    wwv[tid] = __expf(clEnd - clA[tid]) * dtw[tid];
    CLA[(long)blk * 64 + tid] = clA[tid];
  }
  __syncthreads();

#pragma unroll
  for (int k = 0; k < 8; ++k) {
    int e4 = (tid + k * 256) * 4;
    int row = e4 >> 7, col = e4 & 127;
    int t = t0 + row;
    float4 bv = make_float4(0.f,0.f,0.f,0.f), cv = make_float4(0.f,0.f,0.f,0.f);
    if (t < LTOK) {
      const float* rp = base + (long)t * CDIM;
      bv = *(const float4*)(rp + DIN + col);
      cv = *(const float4*)(rp + DIN + DST + col);
    }
    float wv = wwv[row];
    sB[row*136+col]=f2bs(bv.x); sB[row*136+col+1]=f2bs(bv.y);
    sB[row*136+col+2]=f2bs(bv.z); sB[row*136+col+3]=f2bs(bv.w);
    sC[row*136+col]=f2bs(cv.x); sC[row*136+col+1]=f2bs(cv.y);
    sC[row*136+col+2]=f2bs(cv.z); sC[row*136+col+3]=f2bs(cv.w);
    sBT[(col  )*72+row]=f2bs(bv.x*wv); sBT[(col+1)*72+row]=f2bs(bv.y*wv);
    sBT[(col+2)*72+row]=f2bs(bv.z*wv); sBT[(col+3)*72+row]=f2bs(bv.w*wv);
  }
#pragma unroll
  for (int k = 0; k < 4; ++k) {
    int e4 = (tid + k * 256) * 4;
    int row = e4 >> 6, col = e4 & 63;
    int t = t0 + row;
    float4 xv = make_float4(0.f,0.f,0.f,0.f);
    if (t < LTOK) xv = *(const float4*)(base + (long)t * CDIM + h * 64 + col);
    sXT[(col  )*72+row]=f2bs(xv.x); sXT[(col+1)*72+row]=f2bs(xv.y);
    sXT[(col+2)*72+row]=f2bs(xv.z); sXT[(col+3)*72+row]=f2bs(xv.w);
  }
  __syncthreads();

  floatx4 g[4] = {};
#pragma unroll
  for (int kb = 0; kb < 4; ++kb) {
    short8 a = *(const short8*)&sC[(w*16 + lm)*136 + kb*32 + q*8];
#pragma unroll
    for (int ct = 0; ct < 4; ++ct) {
      short8 bb = *(const short8*)&sB[(ct*16 + lm)*136 + kb*32 + q*8];
      g[ct] = __builtin_amdgcn_mfma_f32_16x16x32_bf16(a, bb, g[ct], 0, 0, 0);
    }
  }
#pragma unroll
  for (int ct = 0; ct < 4; ++ct) {
    int tp = ct*16 + lm;
#pragma unroll
    for (int reg = 0; reg < 4; ++reg) {
      int tl = w*16 + q*4 + reg;
      float m = 0.f;
      if (tp <= tl) m = g[ct][reg] * __expf(clA[tl] - clA[tp]) * dtw[tp];
      sM[tl*72 + tp] = f2bs(m);
    }
  }
  __syncthreads();

  floatx4 y[4] = {};
#pragma unroll
  for (int kb = 0; kb < 2; ++kb) {
    short8 a = *(const short8*)&sM[(w*16 + lm)*72 + kb*32 + q*8];
#pragma unroll
    for (int ct = 0; ct < 4; ++ct) {
      short8 bb = *(const short8*)&sXT[(ct*16 + lm)*72 + kb*32 + q*8];
      y[ct] = __builtin_amdgcn_mfma_f32_16x16x32_bf16(a, bb, y[ct], 0, 0, 0);
    }
  }
#pragma unroll
  for (int ct = 0; ct < 4; ++ct) {
    int p = ct*16 + lm;
#pragma unroll
    for (int reg = 0; reg < 4; ++reg) {
      int t = t0 + w*16 + q*4 + reg;
      if (t < LTOK)
        Y[((long)(b * LTOK + t)) * DIN + h * 64 + p] = y[ct][reg];
    }
  }

  floatx4 s[2][4] = {};
#pragma unroll
  for (int kb = 0; kb < 2; ++kb) {
    short8 bfr[4];
#pragma unroll
    for (int ct = 0; ct < 4; ++ct)
      bfr[ct] = *(const short8*)&sXT[(ct*16 + lm)*72 + kb*32 + q*8];
#pragma unroll
    for (int nt = 0; nt < 2; ++nt) {
      short8 a = *(const short8*)&sBT[((w*2+nt)*16 + lm)*72 + kb*32 + q*8];
#pragma unroll
      for (int ct = 0; ct < 4; ++ct)
        s[nt][ct] = __builtin_amdgcn_mfma_f32_16x16x32_bf16(a, bfr[ct], s[nt][ct], 0, 0, 0);
    }
  }
  float* slp = SL + (long)blk * 8192;
#pragma unroll
  for (int nt = 0; nt < 2; ++nt)
#pragma unroll
    for (int ct = 0; ct < 4; ++ct)
#pragma unroll
      for (int reg = 0; reg < 4; ++reg) {
        int n = (w*2+nt)*16 + q*4 + reg;
        int p = ct*16 + lm;
        slp[n*64 + p] = s[nt][ct][reg];
      }
}

// ---------------- SSD phase 2a: in-place sequential combine over chunks ----------------
__global__ __launch_bounds__(256) void k_comb(float* __restrict__ SL,
                                              const float* __restrict__ CLA) {
  int bx = blockIdx.x;
  int piece = bx & 7;
  int hh = bx >> 3;
  int off = piece * 1024 + threadIdx.x * 4;
  float4 s = make_float4(0.f, 0.f, 0.f, 0.f);
  for (int c = 0; c < NCH; ++c) {
    long cb = (long)(hh * NCH + c);
    float* p = SL + cb * 8192 + off;
    float P = __expf(CLA[cb * 64 + 63]);
    float4 tmp = *(float4*)p;
    *(float4*)p = s;
    s.x = fmaf(P, s.x, tmp.x);
    s.y = fmaf(P, s.y, tmp.y);
    s.z = fmaf(P, s.z, tmp.z);
    s.w = fmaf(P, s.w, tmp.w);
  }
}

// ---------------- SSD phase 2b: Y += evec[t] * C_t . S_start  (fully parallel) ----------------
__global__ __launch_bounds__(256) void k_ssd3(const float* __restrict__ xbc,
                                              const float* __restrict__ SL,
                                              const float* __restrict__ CLA,
                                              float* __restrict__ Y) {
  int blk = blockIdx.x;
  int c = blk % NCH;
  int hh = blk / NCH;
  int h = hh & 15, b = hh >> 4;
  int tid = threadIdx.x;
  int tx = tid & 15, ty = tid >> 4;

  __shared__ float Cs[64 * 65];
  __shared__ float Ss[64 * 64];
  __shared__ float evec[64];

  int t0 = c * QC;
  const float* base = xbc + (long)b * LTOK * CDIM;
  const float* slp = SL + (long)blk * 8192;
  if (tid < 64) evec[tid] = __expf(CLA[(long)blk * 64 + tid]);

  float y[4][4] = {};
#pragma unroll
  for (int half = 0; half < 2; ++half) {
    int n0 = half * 64;
    __syncthreads();
#pragma unroll
    for (int k = 0; k < 16; ++k) {
      int e = tid + k * 256;
      int row = e >> 6, col = e & 63;
      int t = t0 + row;
      Cs[row * 65 + col] = (t < LTOK) ? base[(long)t * CDIM + DIN + DST + n0 + col] : 0.f;
    }
#pragma unroll
    for (int k = 0; k < 4; ++k) {
      int e = (tid + k * 256) * 4;
      *(float4*)(Ss + e) = *(const float4*)(slp + n0 * 64 + e);
    }
    __syncthreads();
    for (int n = 0; n < 64; ++n) {
      float cv[4], sv[4];
#pragma unroll
      for (int i = 0; i < 4; ++i) cv[i] = Cs[(ty * 4 + i) * 65 + n];
#pragma unroll
      for (int j = 0; j < 4; ++j) sv[j] = Ss[n * 64 + tx * 4 + j];
#pragma unroll
      for (int i = 0; i < 4; ++i)
#pragma unroll
        for (int j = 0; j < 4; ++j) y[i][j] = fmaf(cv[i], sv[j], y[i][j]);
    }
  }
#pragma unroll
  for (int i = 0; i < 4; ++i) {
    int tl = ty * 4 + i;
    int t = t0 + tl;
    if (t < LTOK) {
      float ev = evec[tl];
      float* yp = Y + ((long)(b * LTOK + t)) * DIN + h * 64 + tx * 4;
#pragma unroll
      for (int j = 0; j < 4; ++j) yp[j] += ev * y[i][j];
    }
  }
}

// ---------------- y(+D*x) + gate silu(z) + RMSNorm, in place on Y ----------------
__global__ __launch_bounds__(256) void k_gaterms(float* __restrict__ Y,
                                                 const float* __restrict__ xbc,
                                                 const float* __restrict__ zx,
                                                 const float* __restrict__ Dv,
                                                 const float* __restrict__ rmsw) {
  long r = blockIdx.x;
  int tid = threadIdx.x;
  int e = tid * 4;
  int h = tid >> 4;
  float4 a = *(const float4*)(Y + r * DIN + e);
  const float4 xv = *(const float4*)(xbc + r * CDIM + e);
  const float4 zv = *(const float4*)(zx + r * EPROJ + e);
  float Dh = Dv[h];
  float y0 = a.x + Dh * xv.x, y1 = a.y + Dh * xv.y;
  float y2 = a.z + Dh * xv.z, y3 = a.w + Dh * xv.w;
  float g0 = y0 * (zv.x / (1.f + expf(-zv.x)));
  float g1 = y1 * (zv.y / (1.f + expf(-zv.y)));
  float g2 = y2 * (zv.z / (1.f + expf(-zv.z)));
  float g3 = y3 * (zv.w / (1.f + expf(-zv.w)));
  __shared__ float red[256];
  red[tid] = g0*g0 + g1*g1 + g2*g2 + g3*g3;
  __syncthreads();
  for (int st = 128; st; st >>= 1) {
    if (tid < st) red[tid] += red[tid + st];
    __syncthreads();
  }
  float scale = rsqrtf(red[0] * (1.0f / 1024.0f) + 1e-5f);
  float4 rw = *(const float4*)(rmsw + e);
  float4 o;
  o.x = g0 * scale * rw.x; o.y = g1 * scale * rw.y;
  o.z = g2 * scale * rw.z; o.w = g3 * scale * rw.w;
  *(float4*)(Y + r * DIN + e) = o;
}

// ---------------- final LayerNorm -> f32 out ----------------
__global__ __launch_bounds__(256) void k_ln(const float* __restrict__ outg,
                                            const float* __restrict__ lng,
                                            const float* __restrict__ lnb,
                                            float* __restrict__ out) {
  int r = blockIdx.x;
  int tid = threadIdx.x;
  const float2 v = *(const float2*)(outg + (long)r * DM + tid * 2);
  __shared__ float red[256];
  red[tid] = v.x + v.y;
  __syncthreads();
  for (int st = 128; st; st >>= 1) { if (tid < st) red[tid] += red[tid + st]; __syncthreads(); }
  float mu = red[0] * (1.0f / 512.0f);
  __syncthreads();
  float dx = v.x - mu, dy = v.y - mu;
  red[tid] = dx * dx + dy * dy;
  __syncthreads();
  for (int st = 128; st; st >>= 1) { if (tid < st) red[tid] += red[tid + st]; __syncthreads(); }
  float sc = rsqrtf(red[0] * (1.0f / 512.0f) + 1e-5f);
  int c = tid * 2;
  out[(long)r * DM + c]     = dx * sc * lng[c] + lnb[c];
  out[(long)r * DM + c + 1] = dy * sc * lng[c + 1] + lnb[c + 1];
}

// ---------------- launch ----------------
extern "C" void kernel_launch(void* const* d_in, const int* in_sizes, int n_in,
                              void* d_out, int out_size, void* d_ws, size_t ws_size,
                              hipStream_t stream) {
  float* ws = (float*)d_ws;
  float* out = (float*)d_out;
  int* rowidx = (int*)(ws + O_RIDX);
  InPtrs ip;
  for (int i = 0; i < 14; ++i) ip.p[i] = d_in[i];

  // slices 0..13 convert (weights 1/4/11 -> bf16); slice 14: OUTG zero + RNG
  hipLaunchKernelGGL(k_convert, dim3(1160, 15), dim3(256), 0, stream, ip, ws, out, rowidx);
  // blocks 2048/2049 write the cls rows of H (fused k_clsrow)
  hipLaunchKernelGGL(k_im2col, dim3(2050), dim3(192), 0, stream,
                     ws + O_CX, ws + O_X3, ws + O_CLS, ws + O_H);
  // conv-embed GEMM (MFMA): (2048 x 192) @ (512 x 192)^T + bias -> H (cls-gap remap)
  hipLaunchKernelGGL(k_bgemm, dim3(4, 16, 1), dim3(256), 0, stream,
                     ws + O_X3, (const uint16_t*)(ws + O_CW), ws + O_H, ws + O_CB,
                     (const int*)nullptr, 2048, 512, 192, 512, 1);
  // in_proj GEMM (MFMA): (2050 x 512) @ (2320 x 512)^T -> zxbcdt
  hipLaunchKernelGGL(k_bgemm, dim3(19, 17, 1), dim3(256), 0, stream,
                     ws + O_H, (const uint16_t*)(ws + O_IPW), ws + O_ZX,
                     (const float*)nullptr, (const int*)nullptr,
                     2050, 2320, 512, 2320, 0);
  // conv + silu (blocks 0..2049) + dt/lga (blocks 2050..2178)
  hipLaunchKernelGGL(k_conv1d, dim3(2179), dim3(256), 0, stream,
                     ws + O_ZX, ws + O_C1W, ws + O_C1B, ws + O_XBC,
                     ws + O_DTB, ws + O_ALOG, ws + O_DT, ws + O_LGA);
  hipLaunchKernelGGL(k_ssd1, dim3(32 * NCH), dim3(256), 0, stream,
                     ws + O_XBC, ws + O_DT, ws + O_LGA, ws + O_Y, ws + O_SL, ws + O_CLA);
  hipLaunchKernelGGL(k_comb, dim3(256), dim3(256), 0, stream, ws + O_SL, ws + O_CLA);
  hipLaunchKernelGGL(k_ssd3, dim3(32 * NCH), dim3(256), 0, stream,
                     ws + O_XBC, ws + O_SL, ws + O_CLA, ws + O_Y);
  hipLaunchKernelGGL(k_gaterms, dim3(2050), dim3(256), 0, stream,
                     ws + O_Y, ws + O_XBC, ws + O_ZX, ws + O_DV, ws + O_RMSW);
  // out_proj GEMM (MFMA, split-K=4 + atomics): (514 x 1024) @ (512 x 1024)^T -> outg
  hipLaunchKernelGGL(k_bgemm, dim3(4, 5, 4), dim3(256), 0, stream,
                     ws + O_Y, (const uint16_t*)(ws + O_OPW), ws + O_OUTG,
                     (const float*)nullptr, rowidx, 514, 512, 1024, 512, 0);
  hipLaunchKernelGGL(k_ln, dim3(514), dim3(256), 0, stream,
                     ws + O_OUTG, ws + O_LNG, ws + O_LNB, out);
}

// Round 15
// 243.412 us; speedup vs baseline: 1.1365x; 1.0046x over previous
//
#include <hip/hip_runtime.h>
#include <hip/hip_bf16.h>
#include <stdint.h>

// ---------------- problem constants ----------------
#define LTOK  1025      // 1024 body + 1 cls
#define NROWS 2050      // B * LTOK
#define DM    512
#define DIN   1024
#define DST   128
#define NHEAD 16
#define HDIM  64
#define CDIM  1280      // DIN + 2*DST
#define EPROJ 2320      // 2*DIN + 2*DST + NHEAD
#define QC    64        // SSD chunk length
#define NCH   17        // ceil(1025/64)

// ---------------- workspace layout (float offsets), ~65.0 MB ----------------
#define O_RIDX   0          // int32 x 514 (reserve 1024)
#define O_CB     1024
#define O_CLS    1536
#define O_C1B    2048
#define O_DTB    3328
#define O_ALOG   3344
#define O_DV     3360
#define O_RMSW   3376
#define O_LNG    4400
#define O_LNB    4912
#define O_CW     5440       // bf16 (ushort)
#define O_IPW    103744     // bf16 (ushort)
#define O_OPW    1291584    // bf16 (ushort)
#define O_C1W    1815872
#define O_CX     1820992
#define O_ZX     1952064
#define O_XBC    6708064
#define O_DT     9332064
#define O_LGA    9364864    // log(dA) = dt * (-exp(A_log))
#define O_Y      9397664    // 2,099,200 floats; overlays H and X3 (dead after in_proj)
#define O_H      9397664    // bf16: 2,099,200 ushorts fit easily
#define O_X3     10447264   // bf16: 393,216 ushorts
#define O_OUTG   11496864   // 263,168
#define O_SL     11760032   // chunk states: 32*17*8192 (S_loc, then in-place S_start)
#define O_CLA    16216480   // within-chunk cumsum logdA: 32*17*64 -> ends 16,251,296

// ---------------- output layout (FLOAT32 elements) ----------------
#define OO_MASK 263168
#define OO_IDR  265216
#define OO_IDK  267264

typedef __attribute__((ext_vector_type(8))) short short8;
typedef __attribute__((ext_vector_type(4))) short shortx4;
typedef __attribute__((ext_vector_type(4))) float floatx4;

__device__ __forceinline__ short f2bs(float f) {
  union { float f; uint32_t u; } v; v.f = f;
  uint32_t r = (v.u + 0x7FFFu + ((v.u >> 16) & 1u)) >> 16;
  return (short)r;
}

struct InPtrs { const void* p[14]; };

// ---------------- threefry2x32 (JAX-compatible) ----------------
__device__ __forceinline__ uint32_t rotl32(uint32_t v, int d) {
  return (v << d) | (v >> (32 - d));
}
__device__ void threefry2x32(uint32_t k0, uint32_t k1, uint32_t c0, uint32_t c1,
                             uint32_t& o0, uint32_t& o1) {
  uint32_t ks0 = k0, ks1 = k1, ks2 = 0x1BD11BDAu ^ k0 ^ k1;
  uint32_t x0 = c0 + ks0, x1 = c1 + ks1;
#define TF_R4(a,b,c,d) \
  x0 += x1; x1 = rotl32(x1,a); x1 ^= x0; \
  x0 += x1; x1 = rotl32(x1,b); x1 ^= x0; \
  x0 += x1; x1 = rotl32(x1,c); x1 ^= x0; \
  x0 += x1; x1 = rotl32(x1,d); x1 ^= x0;
  TF_R4(13,15,26,6)  x0 += ks1; x1 += ks2 + 1u;
  TF_R4(17,29,16,24) x0 += ks2; x1 += ks0 + 2u;
  TF_R4(13,15,26,6)  x0 += ks0; x1 += ks1 + 3u;
  TF_R4(17,29,16,24) x0 += ks1; x1 += ks2 + 4u;
  TF_R4(13,15,26,6)  x0 += ks2; x1 += ks0 + 5u;
#undef TF_R4
  o0 = x0; o1 = x1;
}

// ---------------- input dtype detect ----------------
__device__ int detect_is_f32(const uint32_t* w, int nelem) {
  int nw = nelem / 2; if (nw > 16) nw = 16;
  int insane = 0, lozero = 0, anynz = 0;
  for (int i = 0; i < nw; ++i) {
    uint32_t word = w[i];
    if (word != 0u) anynz = 1;
    uint32_t lo = word & 0xffffu;
    if (lo == 0u) { lozero++; continue; }
    float v = __uint_as_float(lo << 16);
    float a = fabsf(v);
    if (!(a >= 1e-8f && a <= 1e4f)) insane++;
  }
  if (insane >= 2) return 1;
  if (lozero == nw && anynz) return 1;
  return 0;
}

// ---------------- convert + OUTG-zero + RNG (fused) ----------------
__global__ __launch_bounds__(256) void k_convert(InPtrs ptrs, float* ws,
                                                 float* out, int* rowidx) {
  static const int sizes[14] = {131072, 98304, 512, 512, 1187840, 5120, 1280,
                                16, 16, 16, 1024, 524288, 512, 512};
  static const int offs[14]  = {O_CX, O_CW, O_CB, O_CLS, O_IPW, O_C1W, O_C1B,
                                O_DTB, O_ALOG, O_DV, O_RMSW, O_OPW, O_LNG, O_LNB};
  static const int isbf[14]  = {0,1,0,0,1,0,0,0,0,0,0,1,0,0};
  int t = blockIdx.y;
  int tid = threadIdx.x;

  if (t == 14) {
    int bx = blockIdx.x;
    if (bx < 257) {                                 // zero OUTG for split-K atomics
      int base = (bx * 256 + tid) * 4;
      if (base < 263168)
        *(float4*)(ws + O_OUTG + base) = make_float4(0.f, 0.f, 0.f, 0.f);
      return;
    }
    if (bx < 512 || bx >= 544) return;
    // ---- RNG + stable argsort (bx-512 = seg + 16*b) ----
    int rb = bx - 512;
    int seg = rb & 15, b = rb >> 4;
    __shared__ float vals[1024];
    uint32_t fk0, fk1;
    threefry2x32(0u, 0u, 0u, 1u, fk0, fk1);         // fold_in(key(0), 1)
#pragma unroll
    for (int k = 0; k < 4; ++k) {
      int i = tid + k * 256;
      uint32_t o0, o1;
      threefry2x32(fk0, fk1, 0u, (uint32_t)(b * 1024 + i), o0, o1);
      uint32_t bits = o0 ^ o1;
      vals[i] = __uint_as_float((bits >> 9) | 0x3f800000u) - 1.0f;
    }
    __syncthreads();
    int tg = seg * 64 + (tid >> 2);
    int qq = tid & 3;
    float v = vals[tg];
    int r = 0;
    int j0 = qq * 256;
    for (int it = 0; it < 256; ++it) {
      int j = j0 + ((it + qq * 8) & 255);
      float vj = vals[j];
      r += (vj < v || (vj == v && j < tg)) ? 1 : 0;
    }
    r += __shfl_xor(r, 1, 64);
    r += __shfl_xor(r, 2, 64);
    if (qq == 0) {
      out[OO_IDR + b * 1024 + tg] = (float)r;
      out[OO_MASK + b * 1024 + tg] = (r < 256) ? 0.0f : 1.0f;
      if (r < 256) {
        out[OO_IDK + b * 256 + r] = (float)tg;
        rowidx[b * 257 + r] = b * LTOK + tg;
      }
      if (tg == 0) rowidx[b * 257 + 256] = b * LTOK + 1024;
    }
    return;
  }

  int n = sizes[t];
  const uint32_t* w = (const uint32_t*)ptrs.p[t];
  __shared__ int sf;
  if (tid == 0) sf = detect_is_f32(w, n);
  __syncthreads();
  int base = (blockIdx.x * 256 + tid) * 4;
  if (base >= n) return;
  if (isbf[t]) {                                    // write bf16 (ushort)
    ushort4 o;
    if (sf) {
      const float4 vv = *(const float4*)((const float*)w + base);
      o.x = (uint16_t)f2bs(vv.x); o.y = (uint16_t)f2bs(vv.y);
      o.z = (uint16_t)f2bs(vv.z); o.w = (uint16_t)f2bs(vv.w);
    } else {
      const uint32_t* s = w + (base >> 1);
      uint32_t w0 = s[0], w1 = s[1];
      o.x = (uint16_t)(w0 & 0xffffu); o.y = (uint16_t)(w0 >> 16);
      o.z = (uint16_t)(w1 & 0xffffu); o.w = (uint16_t)(w1 >> 16);
    }
    *(ushort4*)((uint16_t*)(ws + offs[t]) + base) = o;
  } else {                                          // write f32
    float* dst = ws + offs[t];
    if (sf) {
      *(float4*)(dst + base) = *(const float4*)((const float*)w + base);
    } else {
      const uint32_t* s = w + (base >> 1);
      uint32_t w0 = s[0], w1 = s[1];
      float4 o;
      o.x = __uint_as_float((w0 & 0xffffu) << 16);
      o.y = __uint_as_float(w0 & 0xffff0000u);
      o.z = __uint_as_float((w1 & 0xffffu) << 16);
      o.w = __uint_as_float(w1 & 0xffff0000u);
      *(float4*)(dst + base) = o;
    }
  }
}

// ---------------- im2col (bf16 out) + fused cls row write (bf16 H) ----------------
__global__ void k_im2col(const float* __restrict__ x, uint16_t* __restrict__ X3,
                         const float* __restrict__ cls, uint16_t* __restrict__ h) {
  int r = blockIdx.x;
  int j = threadIdx.x;
  if (r >= 2048) {                       // fused k_clsrow: blocks 2048, 2049
    int b = r - 2048;
    for (int c = j; c < DM; c += 192)
      h[((long)(b * LTOK + 1024)) * DM + c] = (uint16_t)f2bs(cls[c]);
    return;
  }
  int b = r >> 10, t = r & 1023;
  if (j < 192) {
    int i = j / 3, k = j % 3;
    int tt = t + k - 1;
    float v = (tt >= 0 && tt < 1024) ? x[((long)(b * 1024 + tt)) * 64 + i] : 0.f;
    X3[(long)r * 192 + j] = (uint16_t)f2bs(v);
  }
}

// ---------------- MFMA bf16 GEMM: C = A @ Bw(bf16)^T (+bias) ----------------
// A f32 or bf16 (abf); C f32 or bf16 (obf). 128x128 tile, double-buffered LDS,
// optional split-K over gridDim.z (atomicAdd f32 epilogue, C pre-zeroed, obf=0).
__global__ __launch_bounds__(256) void k_bgemm(
    const void* __restrict__ A, const uint16_t* __restrict__ Bw,
    void* __restrict__ C, const float* __restrict__ bias,
    const int* __restrict__ rowmap, int M, int N, int K, int ldc,
    int cmode, int abf, int obf) {
  __shared__ __align__(16) short sA[2][128 * 40];
  __shared__ __align__(16) short sB[2][128 * 40];
  int tid = threadIdx.x;
  int lane = tid & 63, w = tid >> 6;
  int lm = lane & 15, q = lane >> 4;
  int wm = (w >> 1) * 64, wn = (w & 1) * 64;
  int bm = blockIdx.y * 128, bn = blockIdx.x * 128;
  int gz = gridDim.z;
  int Ks = K / gz;
  int kbase = blockIdx.z * Ks;
  int nk = Ks >> 5;

  int srow[4], scol[4];
  long aoff[4]; bool aok[4]; long boff[4]; bool bok[4];
#pragma unroll
  for (int it = 0; it < 4; ++it) {
    int e4 = (tid + it * 256) * 4;
    srow[it] = e4 >> 5; scol[it] = e4 & 31;
    int gm = bm + srow[it];
    aok[it] = gm < M;
    aoff[it] = aok[it] ? (long)(rowmap ? rowmap[gm] : gm) * K : 0;
    int gn = bn + srow[it];
    bok[it] = gn < N;
    boff[it] = bok[it] ? (long)gn * K : 0;
  }

  auto gload = [&](int kt, float4* vaf, ushort4* vau, ushort4* vb) {
    int kc = kbase + kt * 32;
#pragma unroll
    for (int it = 0; it < 4; ++it) {
      if (abf) {
        if (aok[it]) vau[it] = *(const ushort4*)((const uint16_t*)A + aoff[it] + kc + scol[it]);
        else { vau[it].x = 0; vau[it].y = 0; vau[it].z = 0; vau[it].w = 0; }
      } else {
        vaf[it] = aok[it] ? *(const float4*)((const float*)A + aoff[it] + kc + scol[it])
                          : make_float4(0.f, 0.f, 0.f, 0.f);
      }
      if (bok[it]) vb[it] = *(const ushort4*)(Bw + boff[it] + kc + scol[it]);
      else { vb[it].x = 0; vb[it].y = 0; vb[it].z = 0; vb[it].w = 0; }
    }
  };
  auto sstore = [&](int buf, const float4* vaf, const ushort4* vau, const ushort4* vb) {
#pragma unroll
    for (int it = 0; it < 4; ++it) {
      if (abf)
        *(ushort4*)&sA[buf][srow[it] * 40 + scol[it]] = vau[it];
      else
        *(shortx4*)&sA[buf][srow[it] * 40 + scol[it]] =
            shortx4{f2bs(vaf[it].x), f2bs(vaf[it].y), f2bs(vaf[it].z), f2bs(vaf[it].w)};
      *(ushort4*)&sB[buf][srow[it] * 40 + scol[it]] = vb[it];
    }
  };

  floatx4 acc[4][4] = {};
  float4 vaf[4], naf[4];
  ushort4 vau[4], nau[4], vb[4], nb[4];

  gload(0, vaf, vau, vb);
  sstore(0, vaf, vau, vb);
  for (int kt = 0; kt < nk; ++kt) {
    int cur = kt & 1;
    if (kt + 1 < nk) gload(kt + 1, naf, nau, nb);
    __syncthreads();
    short8 afrag[4], bfrag[4];
#pragma unroll
    for (int i = 0; i < 4; ++i)
      afrag[i] = *(const short8*)&sA[cur][(wm + i * 16 + lm) * 40 + q * 8];
#pragma unroll
    for (int j = 0; j < 4; ++j)
      bfrag[j] = *(const short8*)&sB[cur][(wn + j * 16 + lm) * 40 + q * 8];
#pragma unroll
    for (int i = 0; i < 4; ++i)
#pragma unroll
      for (int j = 0; j < 4; ++j)
        acc[i][j] = __builtin_amdgcn_mfma_f32_16x16x32_bf16(afrag[i], bfrag[j], acc[i][j], 0, 0, 0);
    if (kt + 1 < nk) sstore(1 - cur, naf, nau, nb);
  }

#pragma unroll
  for (int i = 0; i < 4; ++i) {
    int rowl = wm + i * 16 + q * 4;
#pragma unroll
    for (int reg = 0; reg < 4; ++reg) {
      int r = bm + rowl + reg;
      if (r >= M) continue;
      long crow = cmode ? (long)((r >> 10) * LTOK + (r & 1023)) : (long)r;
#pragma unroll
      for (int j = 0; j < 4; ++j) {
        int ccol = bn + wn + j * 16 + lm;
        if (ccol < N) {
          float v = acc[i][j][reg];
          if (gz > 1) {
            atomicAdd(&((float*)C)[crow * ldc + ccol], v);
          } else {
            if (bias) v += bias[ccol];
            if (obf) ((uint16_t*)C)[crow * ldc + ccol] = (uint16_t)f2bs(v);
            else ((float*)C)[crow * ldc + ccol] = v;
          }
        }
      }
    }
  }
}

// ---------------- depthwise causal conv(4) + silu (+ fused dt/lga blocks) ----------------
__global__ __launch_bounds__(256) void k_conv1d(const float* __restrict__ zx,
                                                const float* __restrict__ w,
                                                const float* __restrict__ bias,
                                                float* __restrict__ xbc,
                                                const float* __restrict__ dtb,
                                                const float* __restrict__ alog,
                                                float* __restrict__ dt,
                                                float* __restrict__ lga) {
  long r = blockIdx.x;
  if (r >= NROWS) {                      // fused k_dtda: blocks 2050..2178
    int idx = (int)(r - NROWS) * 256 + threadIdx.x;
    if (idx < NROWS * NHEAD) {
      int rr = idx >> 4, h = idx & 15;
      float xv = zx[(long)rr * EPROJ + (EPROJ - NHEAD) + h] + dtb[h];
      float dtv = (xv > 20.f) ? xv : log1pf(expf(xv));
      dt[idx] = dtv;
      lga[idx] = dtv * (-expf(alog[h]));
    }
    return;
  }
  int b = (int)(r / LTOK), t = (int)(r % LTOK);
  for (int c = threadIdx.x; c < CDIM; c += 256) {
    float acc = bias[c];
    const float* wp = w + c * 4;
#pragma unroll
    for (int k = 0; k < 4; ++k) {
      int tt = t - 3 + k;
      if (tt >= 0)
        acc = fmaf(wp[k], zx[((long)(b * LTOK + tt)) * EPROJ + DIN + c], acc);
    }
    xbc[r * CDIM + c] = acc / (1.f + expf(-acc));
  }
}

// ---------------- SSD phase 1 (MFMA bf16): per (b,h,chunk) intra-chunk work ----------------
__global__ __launch_bounds__(256) void k_ssd1(const float* __restrict__ xbc,
                                              const float* __restrict__ dt,
                                              const float* __restrict__ lga,
                                              float* __restrict__ Y,
                                              float* __restrict__ SL,
                                              float* __restrict__ CLA) {
  int blk = blockIdx.x;
  int c = blk % NCH;
  int hh = blk / NCH;            // h + 16*b
  int h = hh & 15, b = hh >> 4;
  int tid = threadIdx.x;
  int lane = tid & 63, w = tid >> 6;
  int lm = lane & 15, q = lane >> 4;

  __shared__ __align__(16) short sB[64 * 136];
  __shared__ __align__(16) short sC[64 * 136];
  __shared__ __align__(16) short sBT[128 * 72];
  __shared__ __align__(16) short sXT[64 * 72];
  __shared__ __align__(16) short sM[64 * 72];
  __shared__ float dtw[64], clA[64], wwv[64];

  int t0 = c * QC;
  const float* base = xbc + (long)b * LTOK * CDIM;

  if (tid < 64) {
    int t = t0 + tid;
    dtw[tid] = (t < LTOK) ? dt[((long)(b * LTOK + t)) * NHEAD + h] : 0.f;
    clA[tid] = (t < LTOK) ? lga[((long)(b * LTOK + t)) * NHEAD + h] : 0.f;
  }
  __syncthreads();
  if (tid == 0) {
    float s = 0.f;
    for (int i = 0; i < 64; ++i) { s += clA[i]; clA[i] = s; }
  }
  __syncthreads();
  float clEnd = clA[63];
  if (tid < 64) {
    wwv[tid] = __expf(clEnd - clA[tid]) * dtw[tid];
    CLA[(long)blk * 64 + tid] = clA[tid];
  }
  __syncthreads();

#pragma unroll
  for (int k = 0; k < 8; ++k) {
    int e4 = (tid + k * 256) * 4;
    int row = e4 >> 7, col = e4 & 127;
    int t = t0 + row;
    float4 bv = make_float4(0.f,0.f,0.f,0.f), cv = make_float4(0.f,0.f,0.f,0.f);
    if (t < LTOK) {
      const float* rp = base + (long)t * CDIM;
      bv = *(const float4*)(rp + DIN + col);
      cv = *(const float4*)(rp + DIN + DST + col);
    }
    float wv = wwv[row];
    sB[row*136+col]=f2bs(bv.x); sB[row*136+col+1]=f2bs(bv.y);
    sB[row*136+col+2]=f2bs(bv.z); sB[row*136+col+3]=f2bs(bv.w);
    sC[row*136+col]=f2bs(cv.x); sC[row*136+col+1]=f2bs(cv.y);
    sC[row*136+col+2]=f2bs(cv.z); sC[row*136+col+3]=f2bs(cv.w);
    sBT[(col  )*72+row]=f2bs(bv.x*wv); sBT[(col+1)*72+row]=f2bs(bv.y*wv);
    sBT[(col+2)*72+row]=f2bs(bv.z*wv); sBT[(col+3)*72+row]=f2bs(bv.w*wv);
  }
#pragma unroll
  for (int k = 0; k < 4; ++k) {
    int e4 = (tid + k * 256) * 4;
    int row = e4 >> 6, col = e4 & 63;
    int t = t0 + row;
    float4 xv = make_float4(0.f,0.f,0.f,0.f);
    if (t < LTOK) xv = *(const float4*)(base + (long)t * CDIM + h * 64 + col);
    sXT[(col  )*72+row]=f2bs(xv.x); sXT[(col+1)*72+row]=f2bs(xv.y);
    sXT[(col+2)*72+row]=f2bs(xv.z); sXT[(col+3)*72+row]=f2bs(xv.w);
  }
  __syncthreads();

  floatx4 g[4] = {};
#pragma unroll
  for (int kb = 0; kb < 4; ++kb) {
    short8 a = *(const short8*)&sC[(w*16 + lm)*136 + kb*32 + q*8];
#pragma unroll
    for (int ct = 0; ct < 4; ++ct) {
      short8 bb = *(const short8*)&sB[(ct*16 + lm)*136 + kb*32 + q*8];
      g[ct] = __builtin_amdgcn_mfma_f32_16x16x32_bf16(a, bb, g[ct], 0, 0, 0);
    }
  }
#pragma unroll
  for (int ct = 0; ct < 4; ++ct) {
    int tp = ct*16 + lm;
#pragma unroll
    for (int reg = 0; reg < 4; ++reg) {
      int tl = w*16 + q*4 + reg;
      float m = 0.f;
      if (tp <= tl) m = g[ct][reg] * __expf(clA[tl] - clA[tp]) * dtw[tp];
      sM[tl*72 + tp] = f2bs(m);
    }
  }
  __syncthreads();

  floatx4 y[4] = {};
#pragma unroll
  for (int kb = 0; kb < 2; ++kb) {
    short8 a = *(const short8*)&sM[(w*16 + lm)*72 + kb*32 + q*8];
#pragma unroll
    for (int ct = 0; ct < 4; ++ct) {
      short8 bb = *(const short8*)&sXT[(ct*16 + lm)*72 + kb*32 + q*8];
      y[ct] = __builtin_amdgcn_mfma_f32_16x16x32_bf16(a, bb, y[ct], 0, 0, 0);
    }
  }
#pragma unroll
  for (int ct = 0; ct < 4; ++ct) {
    int p = ct*16 + lm;
#pragma unroll
    for (int reg = 0; reg < 4; ++reg) {
      int t = t0 + w*16 + q*4 + reg;
      if (t < LTOK)
        Y[((long)(b * LTOK + t)) * DIN + h * 64 + p] = y[ct][reg];
    }
  }

  floatx4 s[2][4] = {};
#pragma unroll
  for (int kb = 0; kb < 2; ++kb) {
    short8 bfr[4];
#pragma unroll
    for (int ct = 0; ct < 4; ++ct)
      bfr[ct] = *(const short8*)&sXT[(ct*16 + lm)*72 + kb*32 + q*8];
#pragma unroll
    for (int nt = 0; nt < 2; ++nt) {
      short8 a = *(const short8*)&sBT[((w*2+nt)*16 + lm)*72 + kb*32 + q*8];
#pragma unroll
      for (int ct = 0; ct < 4; ++ct)
        s[nt][ct] = __builtin_amdgcn_mfma_f32_16x16x32_bf16(a, bfr[ct], s[nt][ct], 0, 0, 0);
    }
  }
  float* slp = SL + (long)blk * 8192;
#pragma unroll
  for (int nt = 0; nt < 2; ++nt)
#pragma unroll
    for (int ct = 0; ct < 4; ++ct)
#pragma unroll
      for (int reg = 0; reg < 4; ++reg) {
        int n = (w*2+nt)*16 + q*4 + reg;
        int p = ct*16 + lm;
        slp[n*64 + p] = s[nt][ct][reg];
      }
}

// ---------------- SSD phase 2a: in-place sequential combine over chunks ----------------
__global__ __launch_bounds__(256) void k_comb(float* __restrict__ SL,
                                              const float* __restrict__ CLA) {
  int bx = blockIdx.x;
  int piece = bx & 7;
  int hh = bx >> 3;
  int off = piece * 1024 + threadIdx.x * 4;
  float4 s = make_float4(0.f, 0.f, 0.f, 0.f);
  for (int c = 0; c < NCH; ++c) {
    long cb = (long)(hh * NCH + c);
    float* p = SL + cb * 8192 + off;
    float P = __expf(CLA[cb * 64 + 63]);
    float4 tmp = *(float4*)p;
    *(float4*)p = s;
    s.x = fmaf(P, s.x, tmp.x);
    s.y = fmaf(P, s.y, tmp.y);
    s.z = fmaf(P, s.z, tmp.z);
    s.w = fmaf(P, s.w, tmp.w);
  }
}

// ---------------- SSD phase 2b (MFMA bf16): Y += evec[t] * C_t . S_start ----------------
// blk = c + 17*hh. A = C[t][n] (64x128), B = S^T[p][n] (64x128), K = n = 128.
__global__ __launch_bounds__(256) void k_ssd3(const float* __restrict__ xbc,
                                              const float* __restrict__ SL,
                                              const float* __restrict__ CLA,
                                              float* __restrict__ Y) {
  int blk = blockIdx.x;
  int c = blk % NCH;
  int hh = blk / NCH;
  int h = hh & 15, b = hh >> 4;
  int tid = threadIdx.x;
  int lane = tid & 63, w = tid >> 6;
  int lm = lane & 15, q = lane >> 4;

  __shared__ __align__(16) short sC[64 * 136];    // C[t][n]
  __shared__ __align__(16) short sST[64 * 136];   // S^T[p][n]
  __shared__ float evec[64];

  int t0 = c * QC;
  const float* base = xbc + (long)b * LTOK * CDIM;
  const float* slp = SL + (long)blk * 8192;
  if (tid < 64) evec[tid] = __expf(CLA[(long)blk * 64 + tid]);

  // stage C (64 x 128) bf16
#pragma unroll
  for (int k = 0; k < 8; ++k) {
    int e4 = (tid + k * 256) * 4;
    int row = e4 >> 7, col = e4 & 127;
    int t = t0 + row;
    float4 cv = make_float4(0.f,0.f,0.f,0.f);
    if (t < LTOK) cv = *(const float4*)(base + (long)t * CDIM + DIN + DST + col);
    sC[row*136+col]=f2bs(cv.x); sC[row*136+col+1]=f2bs(cv.y);
    sC[row*136+col+2]=f2bs(cv.z); sC[row*136+col+3]=f2bs(cv.w);
  }
  // stage S^T (p x n) bf16 from SL[n][p]
#pragma unroll
  for (int k = 0; k < 8; ++k) {
    int e4 = (tid + k * 256) * 4;
    int n = e4 >> 6, p = e4 & 63;
    float4 sv = *(const float4*)(slp + n * 64 + p);
    sST[(p  )*136+n]=f2bs(sv.x); sST[(p+1)*136+n]=f2bs(sv.y);
    sST[(p+2)*136+n]=f2bs(sv.z); sST[(p+3)*136+n]=f2bs(sv.w);
  }
  __syncthreads();

  floatx4 y[4] = {};
#pragma unroll
  for (int kb = 0; kb < 4; ++kb) {
    short8 a = *(const short8*)&sC[(w*16 + lm)*136 + kb*32 + q*8];
#pragma unroll
    for (int ct = 0; ct < 4; ++ct) {
      short8 bb = *(const short8*)&sST[(ct*16 + lm)*136 + kb*32 + q*8];
      y[ct] = __builtin_amdgcn_mfma_f32_16x16x32_bf16(a, bb, y[ct], 0, 0, 0);
    }
  }
#pragma unroll
  for (int reg = 0; reg < 4; ++reg) {
    int tl = w*16 + q*4 + reg;
    int t = t0 + tl;
    if (t < LTOK) {
      float ev = evec[tl];
#pragma unroll
      for (int ct = 0; ct < 4; ++ct) {
        int p = ct*16 + lm;
        Y[((long)(b * LTOK + t)) * DIN + h * 64 + p] += ev * y[ct][reg];
      }
    }
  }
}

// ---------------- y(+D*x) + gate silu(z) + RMSNorm, in place on Y ----------------
__global__ __launch_bounds__(256) void k_gaterms(float* __restrict__ Y,
                                                 const float* __restrict__ xbc,
                                                 const float* __restrict__ zx,
                                                 const float* __restrict__ Dv,
                                                 const float* __restrict__ rmsw) {
  long r = blockIdx.x;
  int tid = threadIdx.x;
  int e = tid * 4;
  int h = tid >> 4;
  float4 a = *(const float4*)(Y + r * DIN + e);
  const float4 xv = *(const float4*)(xbc + r * CDIM + e);
  const float4 zv = *(const float4*)(zx + r * EPROJ + e);
  float Dh = Dv[h];
  float y0 = a.x + Dh * xv.x, y1 = a.y + Dh * xv.y;
  float y2 = a.z + Dh * xv.z, y3 = a.w + Dh * xv.w;
  float g0 = y0 * (zv.x / (1.f + expf(-zv.x)));
  float g1 = y1 * (zv.y / (1.f + expf(-zv.y)));
  float g2 = y2 * (zv.z / (1.f + expf(-zv.z)));
  float g3 = y3 * (zv.w / (1.f + expf(-zv.w)));
  __shared__ float red[256];
  red[tid] = g0*g0 + g1*g1 + g2*g2 + g3*g3;
  __syncthreads();
  for (int st = 128; st; st >>= 1) {
    if (tid < st) red[tid] += red[tid + st];
    __syncthreads();
  }
  float scale = rsqrtf(red[0] * (1.0f / 1024.0f) + 1e-5f);
  float4 rw = *(const float4*)(rmsw + e);
  float4 o;
  o.x = g0 * scale * rw.x; o.y = g1 * scale * rw.y;
  o.z = g2 * scale * rw.z; o.w = g3 * scale * rw.w;
  *(float4*)(Y + r * DIN + e) = o;
}

// ---------------- final LayerNorm -> f32 out ----------------
__global__ __launch_bounds__(256) void k_ln(const float* __restrict__ outg,
                                            const float* __restrict__ lng,
                                            const float* __restrict__ lnb,
                                            float* __restrict__ out) {
  int r = blockIdx.x;
  int tid = threadIdx.x;
  const float2 v = *(const float2*)(outg + (long)r * DM + tid * 2);
  __shared__ float red[256];
  red[tid] = v.x + v.y;
  __syncthreads();
  for (int st = 128; st; st >>= 1) { if (tid < st) red[tid] += red[tid + st]; __syncthreads(); }
  float mu = red[0] * (1.0f / 512.0f);
  __syncthreads();
  float dx = v.x - mu, dy = v.y - mu;
  red[tid] = dx * dx + dy * dy;
  __syncthreads();
  for (int st = 128; st; st >>= 1) { if (tid < st) red[tid] += red[tid + st]; __syncthreads(); }
  float sc = rsqrtf(red[0] * (1.0f / 512.0f) + 1e-5f);
  int c = tid * 2;
  out[(long)r * DM + c]     = dx * sc * lng[c] + lnb[c];
  out[(long)r * DM + c + 1] = dy * sc * lng[c + 1] + lnb[c + 1];
}

// ---------------- launch ----------------
extern "C" void kernel_launch(void* const* d_in, const int* in_sizes, int n_in,
                              void* d_out, int out_size, void* d_ws, size_t ws_size,
                              hipStream_t stream) {
  float* ws = (float*)d_ws;
  float* out = (float*)d_out;
  int* rowidx = (int*)(ws + O_RIDX);
  InPtrs ip;
  for (int i = 0; i < 14; ++i) ip.p[i] = d_in[i];

  // slices 0..13 convert (weights 1/4/11 -> bf16); slice 14: OUTG zero + RNG
  hipLaunchKernelGGL(k_convert, dim3(1160, 15), dim3(256), 0, stream, ip, ws, out, rowidx);
  // im2col -> bf16 X3; blocks 2048/2049 write cls rows of H (bf16)
  hipLaunchKernelGGL(k_im2col, dim3(2050), dim3(192), 0, stream,
                     ws + O_CX, (uint16_t*)(ws + O_X3), ws + O_CLS, (uint16_t*)(ws + O_H));
  // conv-embed GEMM: (2048 x 192)bf16 @ (512 x 192)bf16^T + bias -> H bf16 (cls-gap remap)
  hipLaunchKernelGGL(k_bgemm, dim3(4, 16, 1), dim3(256), 0, stream,
                     (const void*)(ws + O_X3), (const uint16_t*)(ws + O_CW),
                     (void*)(ws + O_H), ws + O_CB, (const int*)nullptr,
                     2048, 512, 192, 512, 1, 1, 1);
  // in_proj GEMM: (2050 x 512)bf16 @ (2320 x 512)bf16^T -> zxbcdt f32
  hipLaunchKernelGGL(k_bgemm, dim3(19, 17, 1), dim3(256), 0, stream,
                     (const void*)(ws + O_H), (const uint16_t*)(ws + O_IPW),
                     (void*)(ws + O_ZX), (const float*)nullptr, (const int*)nullptr,
                     2050, 2320, 512, 2320, 0, 1, 0);
  // conv + silu (blocks 0..2049) + dt/lga (blocks 2050..2178)
  hipLaunchKernelGGL(k_conv1d, dim3(2179), dim3(256), 0, stream,
                     ws + O_ZX, ws + O_C1W, ws + O_C1B, ws + O_XBC,
                     ws + O_DTB, ws + O_ALOG, ws + O_DT, ws + O_LGA);
  hipLaunchKernelGGL(k_ssd1, dim3(32 * NCH), dim3(256), 0, stream,
                     ws + O_XBC, ws + O_DT, ws + O_LGA, ws + O_Y, ws + O_SL, ws + O_CLA);
  hipLaunchKernelGGL(k_comb, dim3(256), dim3(256), 0, stream, ws + O_SL, ws + O_CLA);
  hipLaunchKernelGGL(k_ssd3, dim3(32 * NCH), dim3(256), 0, stream,
                     ws + O_XBC, ws + O_SL, ws + O_CLA, ws + O_Y);
  hipLaunchKernelGGL(k_gaterms, dim3(2050), dim3(256), 0, stream,
                     ws + O_Y, ws + O_XBC, ws + O_ZX, ws + O_DV, ws + O_RMSW);
  // out_proj GEMM (split-K=4 + atomics): (514 x 1024)f32 @ (512 x 1024)bf16^T -> outg
  hipLaunchKernelGGL(k_bgemm, dim3(4, 5, 4), dim3(256), 0, stream,
                     (const void*)(ws + O_Y), (const uint16_t*)(ws + O_OPW),
                     (void*)(ws + O_OUTG), (const float*)nullptr, rowidx,
                     514, 512, 1024, 512, 0, 0, 0);
  hipLaunchKernelGGL(k_ln, dim3(514), dim3(256), 0, stream,
                     ws + O_OUTG, ws + O_LNG, ws + O_LNB, out);
}

// Round 16
// 241.270 us; speedup vs baseline: 1.1466x; 1.0089x over previous
//
#include <hip/hip_runtime.h>
#include <hip/hip_bf16.h>
#include <stdint.h>

// ---------------- problem constants ----------------
#define LTOK  1025      // 1024 body + 1 cls
#define NROWS 2050      // B * LTOK
#define DM    512
#define DIN   1024
#define DST   128
#define NHEAD 16
#define HDIM  64
#define CDIM  1280      // DIN + 2*DST
#define EPROJ 2320      // 2*DIN + 2*DST + NHEAD
#define QC    64        // SSD chunk length
#define NCH   17        // ceil(1025/64)

// ---------------- workspace layout (float offsets), ~65.0 MB ----------------
#define O_RIDX   0          // int32 x 514 (reserve 1024)
#define O_CB     1024
#define O_CLS    1536
#define O_C1B    2048
#define O_DTB    3328
#define O_ALOG   3344
#define O_DV     3360
#define O_RMSW   3376
#define O_LNG    4400
#define O_LNB    4912
#define O_CW     5440       // bf16 (ushort)
#define O_IPW    103744     // bf16 (ushort)
#define O_OPW    1291584    // bf16 (ushort)
#define O_C1W    1815872
#define O_CX     1820992
#define O_ZX     1952064    // bf16 (ushort) from this round
#define O_XBC    6708064    // bf16 (ushort)
#define O_DT     9332064
#define O_LGA    9364864    // log(dA) = dt * (-exp(A_log))
#define O_Y      9397664    // f32; overlays H and X3 (dead after in_proj)
#define O_H      9397664    // bf16 (ushort)
#define O_X3     10447264   // bf16 (ushort)
#define O_OUTG   11496864   // f32
#define O_SL     11760032   // chunk states f32: 32*17*8192
#define O_CLA    16216480   // within-chunk cumsum logdA: 32*17*64 -> ends 16,251,296

// ---------------- output layout (FLOAT32 elements) ----------------
#define OO_MASK 263168
#define OO_IDR  265216
#define OO_IDK  267264

typedef __attribute__((ext_vector_type(8))) short short8;
typedef __attribute__((ext_vector_type(4))) short shortx4;
typedef __attribute__((ext_vector_type(4))) float floatx4;

__device__ __forceinline__ short f2bs(float f) {
  union { float f; uint32_t u; } v; v.f = f;
  uint32_t r = (v.u + 0x7FFFu + ((v.u >> 16) & 1u)) >> 16;
  return (short)r;
}
__device__ __forceinline__ float bf2f(uint16_t u) {
  return __uint_as_float(((uint32_t)u) << 16);
}

struct InPtrs { const void* p[14]; };

// ---------------- threefry2x32 (JAX-compatible) ----------------
__device__ __forceinline__ uint32_t rotl32(uint32_t v, int d) {
  return (v << d) | (v >> (32 - d));
}
__device__ void threefry2x32(uint32_t k0, uint32_t k1, uint32_t c0, uint32_t c1,
                             uint32_t& o0, uint32_t& o1) {
  uint32_t ks0 = k0, ks1 = k1, ks2 = 0x1BD11BDAu ^ k0 ^ k1;
  uint32_t x0 = c0 + ks0, x1 = c1 + ks1;
#define TF_R4(a,b,c,d) \
  x0 += x1; x1 = rotl32(x1,a); x1 ^= x0; \
  x0 += x1; x1 = rotl32(x1,b); x1 ^= x0; \
  x0 += x1; x1 = rotl32(x1,c); x1 ^= x0; \
  x0 += x1; x1 = rotl32(x1,d); x1 ^= x0;
  TF_R4(13,15,26,6)  x0 += ks1; x1 += ks2 + 1u;
  TF_R4(17,29,16,24) x0 += ks2; x1 += ks0 + 2u;
  TF_R4(13,15,26,6)  x0 += ks0; x1 += ks1 + 3u;
  TF_R4(17,29,16,24) x0 += ks1; x1 += ks2 + 4u;
  TF_R4(13,15,26,6)  x0 += ks2; x1 += ks0 + 5u;
#undef TF_R4
  o0 = x0; o1 = x1;
}

// ---------------- input dtype detect ----------------
__device__ int detect_is_f32(const uint32_t* w, int nelem) {
  int nw = nelem / 2; if (nw > 16) nw = 16;
  int insane = 0, lozero = 0, anynz = 0;
  for (int i = 0; i < nw; ++i) {
    uint32_t word = w[i];
    if (word != 0u) anynz = 1;
    uint32_t lo = word & 0xffffu;
    if (lo == 0u) { lozero++; continue; }
    float v = __uint_as_float(lo << 16);
    float a = fabsf(v);
    if (!(a >= 1e-8f && a <= 1e4f)) insane++;
  }
  if (insane >= 2) return 1;
  if (lozero == nw && anynz) return 1;
  return 0;
}

// ---------------- convert + OUTG-zero + RNG (fused) ----------------
__global__ __launch_bounds__(256) void k_convert(InPtrs ptrs, float* ws,
                                                 float* out, int* rowidx) {
  static const int sizes[14] = {131072, 98304, 512, 512, 1187840, 5120, 1280,
                                16, 16, 16, 1024, 524288, 512, 512};
  static const int offs[14]  = {O_CX, O_CW, O_CB, O_CLS, O_IPW, O_C1W, O_C1B,
                                O_DTB, O_ALOG, O_DV, O_RMSW, O_OPW, O_LNG, O_LNB};
  static const int isbf[14]  = {0,1,0,0,1,0,0,0,0,0,0,1,0,0};
  int t = blockIdx.y;
  int tid = threadIdx.x;

  if (t == 14) {
    int bx = blockIdx.x;
    if (bx < 257) {                                 // zero OUTG for split-K atomics
      int base = (bx * 256 + tid) * 4;
      if (base < 263168)
        *(float4*)(ws + O_OUTG + base) = make_float4(0.f, 0.f, 0.f, 0.f);
      return;
    }
    if (bx < 512 || bx >= 544) return;
    int rb = bx - 512;
    int seg = rb & 15, b = rb >> 4;
    __shared__ float vals[1024];
    uint32_t fk0, fk1;
    threefry2x32(0u, 0u, 0u, 1u, fk0, fk1);         // fold_in(key(0), 1)
#pragma unroll
    for (int k = 0; k < 4; ++k) {
      int i = tid + k * 256;
      uint32_t o0, o1;
      threefry2x32(fk0, fk1, 0u, (uint32_t)(b * 1024 + i), o0, o1);
      uint32_t bits = o0 ^ o1;
      vals[i] = __uint_as_float((bits >> 9) | 0x3f800000u) - 1.0f;
    }
    __syncthreads();
    int tg = seg * 64 + (tid >> 2);
    int qq = tid & 3;
    float v = vals[tg];
    int r = 0;
    int j0 = qq * 256;
    for (int it = 0; it < 256; ++it) {
      int j = j0 + ((it + qq * 8) & 255);
      float vj = vals[j];
      r += (vj < v || (vj == v && j < tg)) ? 1 : 0;
    }
    r += __shfl_xor(r, 1, 64);
    r += __shfl_xor(r, 2, 64);
    if (qq == 0) {
      out[OO_IDR + b * 1024 + tg] = (float)r;
      out[OO_MASK + b * 1024 + tg] = (r < 256) ? 0.0f : 1.0f;
      if (r < 256) {
        out[OO_IDK + b * 256 + r] = (float)tg;
        rowidx[b * 257 + r] = b * LTOK + tg;
      }
      if (tg == 0) rowidx[b * 257 + 256] = b * LTOK + 1024;
    }
    return;
  }

  int n = sizes[t];
  const uint32_t* w = (const uint32_t*)ptrs.p[t];
  __shared__ int sf;
  if (tid == 0) sf = detect_is_f32(w, n);
  __syncthreads();
  int base = (blockIdx.x * 256 + tid) * 4;
  if (base >= n) return;
  if (isbf[t]) {
    ushort4 o;
    if (sf) {
      const float4 vv = *(const float4*)((const float*)w + base);
      o.x = (uint16_t)f2bs(vv.x); o.y = (uint16_t)f2bs(vv.y);
      o.z = (uint16_t)f2bs(vv.z); o.w = (uint16_t)f2bs(vv.w);
    } else {
      const uint32_t* s = w + (base >> 1);
      uint32_t w0 = s[0], w1 = s[1];
      o.x = (uint16_t)(w0 & 0xffffu); o.y = (uint16_t)(w0 >> 16);
      o.z = (uint16_t)(w1 & 0xffffu); o.w = (uint16_t)(w1 >> 16);
    }
    *(ushort4*)((uint16_t*)(ws + offs[t]) + base) = o;
  } else {
    float* dst = ws + offs[t];
    if (sf) {
      *(float4*)(dst + base) = *(const float4*)((const float*)w + base);
    } else {
      const uint32_t* s = w + (base >> 1);
      uint32_t w0 = s[0], w1 = s[1];
      float4 o;
      o.x = __uint_as_float((w0 & 0xffffu) << 16);
      o.y = __uint_as_float(w0 & 0xffff0000u);
      o.z = __uint_as_float((w1 & 0xffffu) << 16);
      o.w = __uint_as_float(w1 & 0xffff0000u);
      *(float4*)(dst + base) = o;
    }
  }
}

// ---------------- im2col (bf16 out) + fused cls row write (bf16 H) ----------------
__global__ void k_im2col(const float* __restrict__ x, uint16_t* __restrict__ X3,
                         const float* __restrict__ cls, uint16_t* __restrict__ h) {
  int r = blockIdx.x;
  int j = threadIdx.x;
  if (r >= 2048) {
    int b = r - 2048;
    for (int c = j; c < DM; c += 192)
      h[((long)(b * LTOK + 1024)) * DM + c] = (uint16_t)f2bs(cls[c]);
    return;
  }
  int b = r >> 10, t = r & 1023;
  if (j < 192) {
    int i = j / 3, k = j % 3;
    int tt = t + k - 1;
    float v = (tt >= 0 && tt < 1024) ? x[((long)(b * 1024 + tt)) * 64 + i] : 0.f;
    X3[(long)r * 192 + j] = (uint16_t)f2bs(v);
  }
}

// ---------------- MFMA bf16 GEMM: C = A @ Bw(bf16)^T (+bias) ----------------
// A f32 or bf16 (abf); C f32 or bf16 (obf). Split-K: atomicAdd f32 (obf=0).
__global__ __launch_bounds__(256) void k_bgemm(
    const void* __restrict__ A, const uint16_t* __restrict__ Bw,
    void* __restrict__ C, const float* __restrict__ bias,
    const int* __restrict__ rowmap, int M, int N, int K, int ldc,
    int cmode, int abf, int obf) {
  __shared__ __align__(16) short sA[2][128 * 40];
  __shared__ __align__(16) short sB[2][128 * 40];
  int tid = threadIdx.x;
  int lane = tid & 63, w = tid >> 6;
  int lm = lane & 15, q = lane >> 4;
  int wm = (w >> 1) * 64, wn = (w & 1) * 64;
  int bm = blockIdx.y * 128, bn = blockIdx.x * 128;
  int gz = gridDim.z;
  int Ks = K / gz;
  int kbase = blockIdx.z * Ks;
  int nk = Ks >> 5;

  int srow[4], scol[4];
  long aoff[4]; bool aok[4]; long boff[4]; bool bok[4];
#pragma unroll
  for (int it = 0; it < 4; ++it) {
    int e4 = (tid + it * 256) * 4;
    srow[it] = e4 >> 5; scol[it] = e4 & 31;
    int gm = bm + srow[it];
    aok[it] = gm < M;
    aoff[it] = aok[it] ? (long)(rowmap ? rowmap[gm] : gm) * K : 0;
    int gn = bn + srow[it];
    bok[it] = gn < N;
    boff[it] = bok[it] ? (long)gn * K : 0;
  }

  auto gload = [&](int kt, float4* vaf, ushort4* vau, ushort4* vb) {
    int kc = kbase + kt * 32;
#pragma unroll
    for (int it = 0; it < 4; ++it) {
      if (abf) {
        if (aok[it]) vau[it] = *(const ushort4*)((const uint16_t*)A + aoff[it] + kc + scol[it]);
        else { vau[it].x = 0; vau[it].y = 0; vau[it].z = 0; vau[it].w = 0; }
      } else {
        vaf[it] = aok[it] ? *(const float4*)((const float*)A + aoff[it] + kc + scol[it])
                          : make_float4(0.f, 0.f, 0.f, 0.f);
      }
      if (bok[it]) vb[it] = *(const ushort4*)(Bw + boff[it] + kc + scol[it]);
      else { vb[it].x = 0; vb[it].y = 0; vb[it].z = 0; vb[it].w = 0; }
    }
  };
  auto sstore = [&](int buf, const float4* vaf, const ushort4* vau, const ushort4* vb) {
#pragma unroll
    for (int it = 0; it < 4; ++it) {
      if (abf)
        *(ushort4*)&sA[buf][srow[it] * 40 + scol[it]] = vau[it];
      else
        *(shortx4*)&sA[buf][srow[it] * 40 + scol[it]] =
            shortx4{f2bs(vaf[it].x), f2bs(vaf[it].y), f2bs(vaf[it].z), f2bs(vaf[it].w)};
      *(ushort4*)&sB[buf][srow[it] * 40 + scol[it]] = vb[it];
    }
  };

  floatx4 acc[4][4] = {};
  float4 vaf[4], naf[4];
  ushort4 vau[4], nau[4], vb[4], nb[4];

  gload(0, vaf, vau, vb);
  sstore(0, vaf, vau, vb);
  for (int kt = 0; kt < nk; ++kt) {
    int cur = kt & 1;
    if (kt + 1 < nk) gload(kt + 1, naf, nau, nb);
    __syncthreads();
    short8 afrag[4], bfrag[4];
#pragma unroll
    for (int i = 0; i < 4; ++i)
      afrag[i] = *(const short8*)&sA[cur][(wm + i * 16 + lm) * 40 + q * 8];
#pragma unroll
    for (int j = 0; j < 4; ++j)
      bfrag[j] = *(const short8*)&sB[cur][(wn + j * 16 + lm) * 40 + q * 8];
#pragma unroll
    for (int i = 0; i < 4; ++i)
#pragma unroll
      for (int j = 0; j < 4; ++j)
        acc[i][j] = __builtin_amdgcn_mfma_f32_16x16x32_bf16(afrag[i], bfrag[j], acc[i][j], 0, 0, 0);
    if (kt + 1 < nk) sstore(1 - cur, naf, nau, nb);
  }

#pragma unroll
  for (int i = 0; i < 4; ++i) {
    int rowl = wm + i * 16 + q * 4;
#pragma unroll
    for (int reg = 0; reg < 4; ++reg) {
      int r = bm + rowl + reg;
      if (r >= M) continue;
      long crow = cmode ? (long)((r >> 10) * LTOK + (r & 1023)) : (long)r;
#pragma unroll
      for (int j = 0; j < 4; ++j) {
        int ccol = bn + wn + j * 16 + lm;
        if (ccol < N) {
          float v = acc[i][j][reg];
          if (gz > 1) {
            atomicAdd(&((float*)C)[crow * ldc + ccol], v);
          } else {
            if (bias) v += bias[ccol];
            if (obf) ((uint16_t*)C)[crow * ldc + ccol] = (uint16_t)f2bs(v);
            else ((float*)C)[crow * ldc + ccol] = v;
          }
        }
      }
    }
  }
}

// ---------------- depthwise causal conv(4) + silu (+ fused dt/lga), bf16 zx/xbc ----------------
__global__ __launch_bounds__(256) void k_conv1d(const uint16_t* __restrict__ zx,
                                                const float* __restrict__ w,
                                                const float* __restrict__ bias,
                                                uint16_t* __restrict__ xbc,
                                                const float* __restrict__ dtb,
                                                const float* __restrict__ alog,
                                                float* __restrict__ dt,
                                                float* __restrict__ lga) {
  long r = blockIdx.x;
  if (r >= NROWS) {                      // fused k_dtda: blocks 2050..2178
    int idx = (int)(r - NROWS) * 256 + threadIdx.x;
    if (idx < NROWS * NHEAD) {
      int rr = idx >> 4, h = idx & 15;
      float xv = bf2f(zx[(long)rr * EPROJ + (EPROJ - NHEAD) + h]) + dtb[h];
      float dtv = (xv > 20.f) ? xv : log1pf(expf(xv));
      dt[idx] = dtv;
      lga[idx] = dtv * (-expf(alog[h]));
    }
    return;
  }
  int b = (int)(r / LTOK), t = (int)(r % LTOK);
  for (int c = threadIdx.x; c < CDIM; c += 256) {
    float acc = bias[c];
    const float* wp = w + c * 4;
#pragma unroll
    for (int k = 0; k < 4; ++k) {
      int tt = t - 3 + k;
      if (tt >= 0)
        acc = fmaf(wp[k], bf2f(zx[((long)(b * LTOK + tt)) * EPROJ + DIN + c]), acc);
    }
    float s = acc / (1.f + expf(-acc));
    xbc[r * CDIM + c] = (uint16_t)f2bs(s);
  }
}

// ---------------- SSD phase 1 (MFMA bf16), bf16 xbc inputs ----------------
__global__ __launch_bounds__(256) void k_ssd1(const uint16_t* __restrict__ xbc,
                                              const float* __restrict__ dt,
                                              const float* __restrict__ lga,
                                              float* __restrict__ Y,
                                              float* __restrict__ SL,
                                              float* __restrict__ CLA) {
  int blk = blockIdx.x;
  int c = blk % NCH;
  int hh = blk / NCH;            // h + 16*b
  int h = hh & 15, b = hh >> 4;
  int tid = threadIdx.x;
  int lane = tid & 63, w = tid >> 6;
  int lm = lane & 15, q = lane >> 4;

  __shared__ __align__(16) short sB[64 * 136];
  __shared__ __align__(16) short sC[64 * 136];
  __shared__ __align__(16) short sBT[128 * 72];
  __shared__ __align__(16) short sXT[64 * 72];
  __shared__ __align__(16) short sM[64 * 72];
  __shared__ float dtw[64], clA[64], wwv[64];

  int t0 = c * QC;
  const uint16_t* base = xbc + (long)b * LTOK * CDIM;

  if (tid < 64) {
    int t = t0 + tid;
    dtw[tid] = (t < LTOK) ? dt[((long)(b * LTOK + t)) * NHEAD + h] : 0.f;
    clA[tid] = (t < LTOK) ? lga[((long)(b * LTOK + t)) * NHEAD + h] : 0.f;
  }
  __syncthreads();
  if (tid == 0) {
    float s = 0.f;
    for (int i = 0; i < 64; ++i) { s += clA[i]; clA[i] = s; }
  }
  __syncthreads();
  float clEnd = clA[63];
  if (tid < 64) {
    wwv[tid] = __expf(clEnd - clA[tid]) * dtw[tid];
    CLA[(long)blk * 64 + tid] = clA[tid];
  }
  __syncthreads();

#pragma unroll
  for (int k = 0; k < 8; ++k) {
    int e4 = (tid + k * 256) * 4;
    int row = e4 >> 7, col = e4 & 127;
    int t = t0 + row;
    ushort4 bv = {0,0,0,0}, cv = {0,0,0,0};
    if (t < LTOK) {
      const uint16_t* rp = base + (long)t * CDIM;
      bv = *(const ushort4*)(rp + DIN + col);
      cv = *(const ushort4*)(rp + DIN + DST + col);
    }
    float wv = wwv[row];
    *(ushort4*)&sB[row*136+col] = bv;
    *(ushort4*)&sC[row*136+col] = cv;
    sBT[(col  )*72+row]=f2bs(bf2f(bv.x)*wv); sBT[(col+1)*72+row]=f2bs(bf2f(bv.y)*wv);
    sBT[(col+2)*72+row]=f2bs(bf2f(bv.z)*wv); sBT[(col+3)*72+row]=f2bs(bf2f(bv.w)*wv);
  }
#pragma unroll
  for (int k = 0; k < 4; ++k) {
    int e4 = (tid + k * 256) * 4;
    int row = e4 >> 6, col = e4 & 63;
    int t = t0 + row;
    ushort4 xv = {0,0,0,0};
    if (t < LTOK) xv = *(const ushort4*)(base + (long)t * CDIM + h * 64 + col);
    sXT[(col  )*72+row]=(short)xv.x; sXT[(col+1)*72+row]=(short)xv.y;
    sXT[(col+2)*72+row]=(short)xv.z; sXT[(col+3)*72+row]=(short)xv.w;
  }
  __syncthreads();

  floatx4 g[4] = {};
#pragma unroll
  for (int kb = 0; kb < 4; ++kb) {
    short8 a = *(const short8*)&sC[(w*16 + lm)*136 + kb*32 + q*8];
#pragma unroll
    for (int ct = 0; ct < 4; ++ct) {
      short8 bb = *(const short8*)&sB[(ct*16 + lm)*136 + kb*32 + q*8];
      g[ct] = __builtin_amdgcn_mfma_f32_16x16x32_bf16(a, bb, g[ct], 0, 0, 0);
    }
  }
#pragma unroll
  for (int ct = 0; ct < 4; ++ct) {
    int tp = ct*16 + lm;
#pragma unroll
    for (int reg = 0; reg < 4; ++reg) {
      int tl = w*16 + q*4 + reg;
      float m = 0.f;
      if (tp <= tl) m = g[ct][reg] * __expf(clA[tl] - clA[tp]) * dtw[tp];
      sM[tl*72 + tp] = f2bs(m);
    }
  }
  __syncthreads();

  floatx4 y[4] = {};
#pragma unroll
  for (int kb = 0; kb < 2; ++kb) {
    short8 a = *(const short8*)&sM[(w*16 + lm)*72 + kb*32 + q*8];
#pragma unroll
    for (int ct = 0; ct < 4; ++ct) {
      short8 bb = *(const short8*)&sXT[(ct*16 + lm)*72 + kb*32 + q*8];
      y[ct] = __builtin_amdgcn_mfma_f32_16x16x32_bf16(a, bb, y[ct], 0, 0, 0);
    }
  }
#pragma unroll
  for (int ct = 0; ct < 4; ++ct) {
    int p = ct*16 + lm;
#pragma unroll
    for (int reg = 0; reg < 4; ++reg) {
      int t = t0 + w*16 + q*4 + reg;
      if (t < LTOK)
        Y[((long)(b * LTOK + t)) * DIN + h * 64 + p] = y[ct][reg];
    }
  }

  floatx4 s[2][4] = {};
#pragma unroll
  for (int kb = 0; kb < 2; ++kb) {
    short8 bfr[4];
#pragma unroll
    for (int ct = 0; ct < 4; ++ct)
      bfr[ct] = *(const short8*)&sXT[(ct*16 + lm)*72 + kb*32 + q*8];
#pragma unroll
    for (int nt = 0; nt < 2; ++nt) {
      short8 a = *(const short8*)&sBT[((w*2+nt)*16 + lm)*72 + kb*32 + q*8];
#pragma unroll
      for (int ct = 0; ct < 4; ++ct)
        s[nt][ct] = __builtin_amdgcn_mfma_f32_16x16x32_bf16(a, bfr[ct], s[nt][ct], 0, 0, 0);
    }
  }
  float* slp = SL + (long)blk * 8192;
#pragma unroll
  for (int nt = 0; nt < 2; ++nt)
#pragma unroll
    for (int ct = 0; ct < 4; ++ct)
#pragma unroll
      for (int reg = 0; reg < 4; ++reg) {
        int n = (w*2+nt)*16 + q*4 + reg;
        int p = ct*16 + lm;
        slp[n*64 + p] = s[nt][ct][reg];
      }
}

// ---------------- SSD phase 2a: in-place sequential combine over chunks ----------------
__global__ __launch_bounds__(256) void k_comb(float* __restrict__ SL,
                                              const float* __restrict__ CLA) {
  int bx = blockIdx.x;
  int piece = bx & 7;
  int hh = bx >> 3;
  int off = piece * 1024 + threadIdx.x * 4;
  float4 s = make_float4(0.f, 0.f, 0.f, 0.f);
  for (int c = 0; c < NCH; ++c) {
    long cb = (long)(hh * NCH + c);
    float* p = SL + cb * 8192 + off;
    float P = __expf(CLA[cb * 64 + 63]);
    float4 tmp = *(float4*)p;
    *(float4*)p = s;
    s.x = fmaf(P, s.x, tmp.x);
    s.y = fmaf(P, s.y, tmp.y);
    s.z = fmaf(P, s.z, tmp.z);
    s.w = fmaf(P, s.w, tmp.w);
  }
}

// ---------------- SSD phase 2b (MFMA bf16): Y += evec[t] * C_t . S_start ----------------
__global__ __launch_bounds__(256) void k_ssd3(const uint16_t* __restrict__ xbc,
                                              const float* __restrict__ SL,
                                              const float* __restrict__ CLA,
                                              float* __restrict__ Y) {
  int blk = blockIdx.x;
  int c = blk % NCH;
  int hh = blk / NCH;
  int h = hh & 15, b = hh >> 4;
  int tid = threadIdx.x;
  int lane = tid & 63, w = tid >> 6;
  int lm = lane & 15, q = lane >> 4;

  __shared__ __align__(16) short sC[64 * 136];    // C[t][n]
  __shared__ __align__(16) short sST[64 * 136];   // S^T[p][n]
  __shared__ float evec[64];

  int t0 = c * QC;
  const uint16_t* base = xbc + (long)b * LTOK * CDIM;
  const float* slp = SL + (long)blk * 8192;
  if (tid < 64) evec[tid] = __expf(CLA[(long)blk * 64 + tid]);

#pragma unroll
  for (int k = 0; k < 8; ++k) {
    int e4 = (tid + k * 256) * 4;
    int row = e4 >> 7, col = e4 & 127;
    int t = t0 + row;
    ushort4 cv = {0,0,0,0};
    if (t < LTOK) cv = *(const ushort4*)(base + (long)t * CDIM + DIN + DST + col);
    *(ushort4*)&sC[row*136+col] = cv;
  }
#pragma unroll
  for (int k = 0; k < 8; ++k) {
    int e4 = (tid + k * 256) * 4;
    int n = e4 >> 6, p = e4 & 63;
    float4 sv = *(const float4*)(slp + n * 64 + p);
    sST[(p  )*136+n]=f2bs(sv.x); sST[(p+1)*136+n]=f2bs(sv.y);
    sST[(p+2)*136+n]=f2bs(sv.z); sST[(p+3)*136+n]=f2bs(sv.w);
  }
  __syncthreads();

  floatx4 y[4] = {};
#pragma unroll
  for (int kb = 0; kb < 4; ++kb) {
    short8 a = *(const short8*)&sC[(w*16 + lm)*136 + kb*32 + q*8];
#pragma unroll
    for (int ct = 0; ct < 4; ++ct) {
      short8 bb = *(const short8*)&sST[(ct*16 + lm)*136 + kb*32 + q*8];
      y[ct] = __builtin_amdgcn_mfma_f32_16x16x32_bf16(a, bb, y[ct], 0, 0, 0);
    }
  }
#pragma unroll
  for (int reg = 0; reg < 4; ++reg) {
    int tl = w*16 + q*4 + reg;
    int t = t0 + tl;
    if (t < LTOK) {
      float ev = evec[tl];
#pragma unroll
      for (int ct = 0; ct < 4; ++ct) {
        int p = ct*16 + lm;
        Y[((long)(b * LTOK + t)) * DIN + h * 64 + p] += ev * y[ct][reg];
      }
    }
  }
}

// ---------------- y(+D*x) + gate silu(z) + RMSNorm, bf16 xbc/zx ----------------
__global__ __launch_bounds__(256) void k_gaterms(float* __restrict__ Y,
                                                 const uint16_t* __restrict__ xbc,
                                                 const uint16_t* __restrict__ zx,
                                                 const float* __restrict__ Dv,
                                                 const float* __restrict__ rmsw) {
  long r = blockIdx.x;
  int tid = threadIdx.x;
  int e = tid * 4;
  int h = tid >> 4;
  float4 a = *(const float4*)(Y + r * DIN + e);
  const ushort4 xu = *(const ushort4*)(xbc + r * CDIM + e);
  const ushort4 zu = *(const ushort4*)(zx + r * EPROJ + e);
  float Dh = Dv[h];
  float y0 = a.x + Dh * bf2f(xu.x), y1 = a.y + Dh * bf2f(xu.y);
  float y2 = a.z + Dh * bf2f(xu.z), y3 = a.w + Dh * bf2f(xu.w);
  float z0 = bf2f(zu.x), z1 = bf2f(zu.y), z2 = bf2f(zu.z), z3 = bf2f(zu.w);
  float g0 = y0 * (z0 / (1.f + expf(-z0)));
  float g1 = y1 * (z1 / (1.f + expf(-z1)));
  float g2 = y2 * (z2 / (1.f + expf(-z2)));
  float g3 = y3 * (z3 / (1.f + expf(-z3)));
  __shared__ float red[256];
  red[tid] = g0*g0 + g1*g1 + g2*g2 + g3*g3;
  __syncthreads();
  for (int st = 128; st; st >>= 1) {
    if (tid < st) red[tid] += red[tid + st];
    __syncthreads();
  }
  float scale = rsqrtf(red[0] * (1.0f / 1024.0f) + 1e-5f);
  float4 rw = *(const float4*)(rmsw + e);
  float4 o;
  o.x = g0 * scale * rw.x; o.y = g1 * scale * rw.y;
  o.z = g2 * scale * rw.z; o.w = g3 * scale * rw.w;
  *(float4*)(Y + r * DIN + e) = o;
}

// ---------------- final LayerNorm -> f32 out ----------------
__global__ __launch_bounds__(256) void k_ln(const float* __restrict__ outg,
                                            const float* __restrict__ lng,
                                            const float* __restrict__ lnb,
                                            float* __restrict__ out) {
  int r = blockIdx.x;
  int tid = threadIdx.x;
  const float2 v = *(const float2*)(outg + (long)r * DM + tid * 2);
  __shared__ float red[256];
  red[tid] = v.x + v.y;
  __syncthreads();
  for (int st = 128; st; st >>= 1) { if (tid < st) red[tid] += red[tid + st]; __syncthreads(); }
  float mu = red[0] * (1.0f / 512.0f);
  __syncthreads();
  float dx = v.x - mu, dy = v.y - mu;
  red[tid] = dx * dx + dy * dy;
  __syncthreads();
  for (int st = 128; st; st >>= 1) { if (tid < st) red[tid] += red[tid + st]; __syncthreads(); }
  float sc = rsqrtf(red[0] * (1.0f / 512.0f) + 1e-5f);
  int c = tid * 2;
  out[(long)r * DM + c]     = dx * sc * lng[c] + lnb[c];
  out[(long)r * DM + c + 1] = dy * sc * lng[c + 1] + lnb[c + 1];
}

// ---------------- launch ----------------
extern "C" void kernel_launch(void* const* d_in, const int* in_sizes, int n_in,
                              void* d_out, int out_size, void* d_ws, size_t ws_size,
                              hipStream_t stream) {
  float* ws = (float*)d_ws;
  float* out = (float*)d_out;
  int* rowidx = (int*)(ws + O_RIDX);
  InPtrs ip;
  for (int i = 0; i < 14; ++i) ip.p[i] = d_in[i];

  hipLaunchKernelGGL(k_convert, dim3(1160, 15), dim3(256), 0, stream, ip, ws, out, rowidx);
  hipLaunchKernelGGL(k_im2col, dim3(2050), dim3(192), 0, stream,
                     ws + O_CX, (uint16_t*)(ws + O_X3), ws + O_CLS, (uint16_t*)(ws + O_H));
  // conv-embed GEMM: bf16 in/out (cls-gap remap)
  hipLaunchKernelGGL(k_bgemm, dim3(4, 16, 1), dim3(256), 0, stream,
                     (const void*)(ws + O_X3), (const uint16_t*)(ws + O_CW),
                     (void*)(ws + O_H), ws + O_CB, (const int*)nullptr,
                     2048, 512, 192, 512, 1, 1, 1);
  // in_proj GEMM: bf16 A/B -> ZX bf16
  hipLaunchKernelGGL(k_bgemm, dim3(19, 17, 1), dim3(256), 0, stream,
                     (const void*)(ws + O_H), (const uint16_t*)(ws + O_IPW),
                     (void*)(ws + O_ZX), (const float*)nullptr, (const int*)nullptr,
                     2050, 2320, 512, 2320, 0, 1, 1);
  // conv + silu (bf16 zx -> bf16 xbc) + dt/lga blocks
  hipLaunchKernelGGL(k_conv1d, dim3(2179), dim3(256), 0, stream,
                     (const uint16_t*)(ws + O_ZX), ws + O_C1W, ws + O_C1B,
                     (uint16_t*)(ws + O_XBC),
                     ws + O_DTB, ws + O_ALOG, ws + O_DT, ws + O_LGA);
  hipLaunchKernelGGL(k_ssd1, dim3(32 * NCH), dim3(256), 0, stream,
                     (const uint16_t*)(ws + O_XBC), ws + O_DT, ws + O_LGA,
                     ws + O_Y, ws + O_SL, ws + O_CLA);
  hipLaunchKernelGGL(k_comb, dim3(256), dim3(256), 0, stream, ws + O_SL, ws + O_CLA);
  hipLaunchKernelGGL(k_ssd3, dim3(32 * NCH), dim3(256), 0, stream,
                     (const uint16_t*)(ws + O_XBC), ws + O_SL, ws + O_CLA, ws + O_Y);
  hipLaunchKernelGGL(k_gaterms, dim3(2050), dim3(256), 0, stream,
                     ws + O_Y, (const uint16_t*)(ws + O_XBC),
                     (const uint16_t*)(ws + O_ZX), ws + O_DV, ws + O_RMSW);
  // out_proj GEMM (split-K=4 + atomics): (514 x 1024)f32 @ bf16^T -> outg
  hipLaunchKernelGGL(k_bgemm, dim3(4, 5, 4), dim3(256), 0, stream,
                     (const void*)(ws + O_Y), (const uint16_t*)(ws + O_OPW),
                     (void*)(ws + O_OUTG), (const float*)nullptr, rowidx,
                     514, 512, 1024, 512, 0, 0, 0);
  hipLaunchKernelGGL(k_ln, dim3(514), dim3(256), 0, stream,
                     ws + O_OUTG, ws + O_LNG, ws + O_LNB, out);
}